// Round 3
// baseline (1053.026 us; speedup 1.0000x reference)
//
#include <hip/hip_runtime.h>
#include <math.h>

typedef unsigned int uint32;

__device__ inline uint32 bf16rn(float x){
  uint32 b = __float_as_uint(x);
  return (b + 0x7fffu + ((b>>16)&1u)) >> 16;
}
__device__ inline float bf16lo(uint32 v){ return __uint_as_float(v<<16); }
__device__ inline float bf16hi(uint32 v){ return __uint_as_float(v & 0xffff0000u); }

#define BKT_SHIFT 9            // 512 nodes per bucket
#define SUBS 4
#define SUBCAP 4096
#define OVFCAP 32768

// ---------------- bucketing pass: deg histogram + pair scatter ----------------
__device__ inline void bucket_one(int s, int d, int sub, int* __restrict__ deg,
                                  int* __restrict__ subcnt, uint2* __restrict__ pairs,
                                  int* __restrict__ ovf_cnt, uint2* __restrict__ ovf){
  atomicAdd(&deg[d], 1);
  int b = d >> BKT_SHIFT;
  int pos = atomicAdd(&subcnt[b*SUBS + sub], 1);
  if (pos < SUBCAP) pairs[(size_t)(b*SUBS + sub)*SUBCAP + pos] = make_uint2((uint32)s,(uint32)d);
  else { int o = atomicAdd(ovf_cnt,1); if (o < OVFCAP) ovf[o] = make_uint2((uint32)s,(uint32)d); }
}

__global__ __launch_bounds__(256) void k_bucket(const int* __restrict__ src, const int* __restrict__ dst,
                        int* __restrict__ deg, int* __restrict__ subcnt, uint2* __restrict__ pairs,
                        int* __restrict__ ovf_cnt, uint2* __restrict__ ovf, int E){
  int base = (blockIdx.x*256 + threadIdx.x)*4;
  int sub = blockIdx.x & (SUBS-1);
  if (base + 3 < E){
    int4 s4 = *(const int4*)&src[base];
    int4 d4 = *(const int4*)&dst[base];
    bucket_one(s4.x, d4.x, sub, deg, subcnt, pairs, ovf_cnt, ovf);
    bucket_one(s4.y, d4.y, sub, deg, subcnt, pairs, ovf_cnt, ovf);
    bucket_one(s4.z, d4.z, sub, deg, subcnt, pairs, ovf_cnt, ovf);
    bucket_one(s4.w, d4.w, sub, deg, subcnt, pairs, ovf_cnt, ovf);
  } else {
    for (int i=base; i<E; i++) bucket_one(src[i], dst[i], sub, deg, subcnt, pairs, ovf_cnt, ovf);
  }
}

// ---------------- scans ----------------
__global__ __launch_bounds__(256) void k_scanA(const int* __restrict__ deg, int* __restrict__ partials, int N){
  int base = blockIdx.x*1024;
  int t = threadIdx.x;
  int s = 0;
  for (int j=t; j<1024; j+=256){ int idx=base+j; if (idx<N) s += deg[idx]; }
  for (int off=32; off; off>>=1) s += __shfl_down(s, off);
  __shared__ int red[4];
  int wid=t>>6, lane=t&63;
  if (lane==0) red[wid]=s;
  __syncthreads();
  if (t==0) partials[blockIdx.x] = red[0]+red[1]+red[2]+red[3];
}

__global__ __launch_bounds__(128) void k_scanB(int* partials, int nb, int* row_ptr, int N){
  __shared__ int lds[128];
  int t = threadIdx.x;
  int v = (t<nb)? partials[t] : 0;
  lds[t]=v; __syncthreads();
  int x=v;
  for (int off=1; off<128; off<<=1){
    int y = (t>=off)? lds[t-off] : 0;
    __syncthreads();
    x += y; lds[t]=x;
    __syncthreads();
  }
  if (t<nb) partials[t] = x - v;
  if (t==127) row_ptr[N] = x;
}

__global__ __launch_bounds__(1024) void k_scanC(const int* __restrict__ deg, const int* __restrict__ partials,
                        int* __restrict__ row_ptr, int* __restrict__ cursor, int N){
  __shared__ int lds[1024];
  int base = blockIdx.x*1024;
  int t = threadIdx.x;
  int idx = base+t;
  int v = (idx<N)? deg[idx] : 0;
  lds[t]=v; __syncthreads();
  int x=v;
  for (int off=1; off<1024; off<<=1){
    int y = (t>=off)? lds[t-off] : 0;
    __syncthreads();
    x += y; lds[t]=x;
    __syncthreads();
  }
  if (idx<N){
    int out = partials[blockIdx.x] + x - v;
    row_ptr[idx]=out; cursor[idx]=out;
  }
}

// ---------------- build CSR from buckets (one block per bucket) ----------------
__global__ __launch_bounds__(1024) void k_build(const int* __restrict__ subcnt, const uint2* __restrict__ pairs,
                        int* __restrict__ cursor, int* __restrict__ csr_src){
  int b = blockIdx.x;
  #pragma unroll
  for (int sub=0; sub<SUBS; sub++){
    int cnt = subcnt[b*SUBS + sub]; if (cnt > SUBCAP) cnt = SUBCAP;
    const uint2* p = pairs + (size_t)(b*SUBS + sub)*SUBCAP;
    for (int i=threadIdx.x; i<cnt; i+=1024){
      uint2 e = p[i];
      int pos = atomicAdd(&cursor[e.y], 1);
      csr_src[pos] = (int)e.x;
    }
  }
}

__global__ __launch_bounds__(256) void k_overflow(const int* __restrict__ ovf_cnt, const uint2* __restrict__ ovf,
                        int* __restrict__ cursor, int* __restrict__ csr_src){
  int n = *ovf_cnt; if (n > OVFCAP) n = OVFCAP;
  for (int i=threadIdx.x; i<n; i+=256){
    uint2 e = ovf[i];
    int pos = atomicAdd(&cursor[e.y], 1);
    csr_src[pos] = (int)e.x;
  }
}

// ---------------- GEMM [N,128]x[128,128] -> bf16 F + fused el/er ----------------
__global__ __launch_bounds__(256) void k_gemm128(const float* __restrict__ A, const float* __restrict__ W,
                                                 const float* __restrict__ al, const float* __restrict__ ar,
                                                 unsigned short* __restrict__ Fb,
                                                 float* __restrict__ el, float* __restrict__ er, int N){
  __shared__ float hs[32][68];
  __shared__ float ws[32][128];
  int t = threadIdx.x;
  int rowBase = blockIdx.x*64;
  int rg8 = (t>>5)*8;
  int cq  = (t&31)*4;
  float acc[8][4] = {};
  for (int kc=0; kc<128; kc+=32){
    {
      int row = t>>2; int kk = (t&3)*8;
      int grow = rowBase+row;
      float4 v0, v1;
      if (grow < N){
        v0 = *(const float4*)&A[(size_t)grow*128 + kc + kk];
        v1 = *(const float4*)&A[(size_t)grow*128 + kc + kk + 4];
      } else { v0 = make_float4(0,0,0,0); v1 = v0; }
      hs[kk+0][row]=v0.x; hs[kk+1][row]=v0.y; hs[kk+2][row]=v0.z; hs[kk+3][row]=v0.w;
      hs[kk+4][row]=v1.x; hs[kk+5][row]=v1.y; hs[kk+6][row]=v1.z; hs[kk+7][row]=v1.w;
    }
    {
      int k = t>>3; int c0 = (t&7)*16;
      const float4* wp = (const float4*)&W[(size_t)(kc+k)*128 + c0];
      float4 w0=wp[0], w1=wp[1], w2=wp[2], w3=wp[3];
      *(float4*)&ws[k][c0+ 0]=w0; *(float4*)&ws[k][c0+ 4]=w1;
      *(float4*)&ws[k][c0+ 8]=w2; *(float4*)&ws[k][c0+12]=w3;
    }
    __syncthreads();
    #pragma unroll
    for (int k=0;k<32;k++){
      float4 bv  = *(const float4*)&ws[k][cq];
      float4 av0 = *(const float4*)&hs[k][rg8];
      float4 av1 = *(const float4*)&hs[k][rg8+4];
      float a8[8] = {av0.x,av0.y,av0.z,av0.w,av1.x,av1.y,av1.z,av1.w};
      float b4[4] = {bv.x,bv.y,bv.z,bv.w};
      #pragma unroll
      for (int r=0;r<8;r++)
        #pragma unroll
        for (int c=0;c<4;c++)
          acc[r][c] = fmaf(a8[r], b4[c], acc[r][c]);
    }
    __syncthreads();
  }
  float al4[4], ar4[4];
  #pragma unroll
  for (int i=0;i<4;i++){ al4[i]=al[cq+i]; ar4[i]=ar[cq+i]; }
  int c = t&31;
  int h = c>>3;
  int rowTop = rowBase + rg8;
  #pragma unroll
  for (int r=0;r<8;r++){
    int row = rowTop + r;
    if (row < N){
      uint32 u0 = bf16rn(acc[r][0]) | (bf16rn(acc[r][1])<<16);
      uint32 u1 = bf16rn(acc[r][2]) | (bf16rn(acc[r][3])<<16);
      *(uint2*)(Fb + (size_t)row*128 + cq) = make_uint2(u0,u1);
    }
    float pl = acc[r][0]*al4[0]+acc[r][1]*al4[1]+acc[r][2]*al4[2]+acc[r][3]*al4[3];
    float pr = acc[r][0]*ar4[0]+acc[r][1]*ar4[1]+acc[r][2]*ar4[2]+acc[r][3]*ar4[3];
    pl += __shfl_xor(pl,1); pr += __shfl_xor(pr,1);
    pl += __shfl_xor(pl,2); pr += __shfl_xor(pr,2);
    pl += __shfl_xor(pl,4); pr += __shfl_xor(pr,4);
    if ((c&7)==0 && row < N){ el[(size_t)row*4+h]=pl; er[(size_t)row*4+h]=pr; }
  }
}

// ---------------- fused edge-softmax + aggregation (H=4,D=32), bf16 gather ----------------
#define AGG_STEP(sY) { int s_=(sY); \
    float x_=el[(size_t)s_*4+h]+erv; x_=x_>0.f?x_:0.2f*x_; x_=__expf(x_); \
    uint32 v_=Fu[(size_t)s_*64+lane]; \
    denom+=x_; acc0=fmaf(x_,bf16lo(v_),acc0); acc1=fmaf(x_,bf16hi(v_),acc1); }

__global__ __launch_bounds__(256) void k_agg128(const uint32* __restrict__ Fu, const float* __restrict__ el,
                         const float* __restrict__ er, const int* __restrict__ row_ptr,
                         const int* __restrict__ csr_src, float* __restrict__ out, int N){
  int node = (blockIdx.x*blockDim.x + threadIdx.x)>>6;
  int lane = threadIdx.x & 63;
  if (node >= N) return;
  int h = lane>>4;
  float erv = er[(size_t)node*4+h];
  int beg = row_ptr[node], end = row_ptr[node+1];
  int deg = end - beg;
  int sv = (beg + lane < end) ? csr_src[beg+lane] : 0;
  float acc0=0.f, acc1=0.f, denom=0.f;
  int nmain = deg > 64 ? 64 : deg;
  int i = 0;
  for (; i+8 <= nmain; i+=8){
    int s0=__shfl(sv,i+0), s1=__shfl(sv,i+1), s2=__shfl(sv,i+2), s3=__shfl(sv,i+3);
    int s4=__shfl(sv,i+4), s5=__shfl(sv,i+5), s6=__shfl(sv,i+6), s7=__shfl(sv,i+7);
    AGG_STEP(s0); AGG_STEP(s1); AGG_STEP(s2); AGG_STEP(s3);
    AGG_STEP(s4); AGG_STEP(s5); AGG_STEP(s6); AGG_STEP(s7);
  }
  for (; i<nmain; i++){ int s=__shfl(sv,i); AGG_STEP(s); }
  if (deg > 64){
    for (int e=beg+64; e<end; e++){ int s=csr_src[e]; AGG_STEP(s); }
  }
  float inv = 1.0f/denom;
  float o0 = acc0*inv, o1 = acc1*inv;
  o0 = o0>0.f ? o0 : expm1f(o0);
  o1 = o1>0.f ? o1 : expm1f(o1);
  *(float2*)&out[(size_t)node*128 + lane*2] = make_float2(o0,o1);
}

// ---------------- layer-2 GEMM [N,128]x[128,40] fused with el2/er2, bf16 F ----------------
__global__ __launch_bounds__(256) void k_gemm40(const float* __restrict__ A, const float* __restrict__ W,
                        const float* __restrict__ al, const float* __restrict__ ar,
                        unsigned short* __restrict__ Fb, float* __restrict__ el, float* __restrict__ er, int N){
  __shared__ float ws[5120];
  __shared__ float sal[64], sar[64];
  int t = threadIdx.x;
  for (int i=t; i<5120; i+=256) ws[i] = W[i];
  if (t<40){ sal[t]=al[t]; sar[t]=ar[t]; }
  else if (t<64){ sal[t]=0.f; sar[t]=0.f; }
  __syncthreads();
  int node = blockIdx.x*4 + (t>>6);
  int lane = t & 63;
  if (node >= N) return;
  int l40 = lane<40 ? lane : 0;
  const float* a = A + (size_t)node*128;
  float acc = 0.f;
  #pragma unroll
  for (int k=0;k<128;k+=4){
    float4 hv = *(const float4*)&a[k];
    acc = fmaf(hv.x, ws[(k+0)*40+l40], acc);
    acc = fmaf(hv.y, ws[(k+1)*40+l40], acc);
    acc = fmaf(hv.z, ws[(k+2)*40+l40], acc);
    acc = fmaf(hv.w, ws[(k+3)*40+l40], acc);
  }
  bool act = lane<40;
  float pl = act ? acc*sal[lane] : 0.f;
  float pr = act ? acc*sar[lane] : 0.f;
  for (int off=32; off; off>>=1){ pl += __shfl_xor(pl, off); pr += __shfl_xor(pr, off); }
  if (lane==0){ el[node]=pl; er[node]=pr; }
  if (act) Fb[(size_t)node*40 + lane] = (unsigned short)bf16rn(acc);
}

// ---------------- final aggregation (H=1,D=40) + log_softmax, bf16 gather ----------------
__global__ __launch_bounds__(256) void k_agg40(const unsigned short* __restrict__ Fb, const float* __restrict__ el,
                       const float* __restrict__ er, const int* __restrict__ row_ptr,
                       const int* __restrict__ csr_src, float* __restrict__ out, int N){
  int node = (blockIdx.x*blockDim.x + threadIdx.x)>>6;
  int lane = threadIdx.x & 63;
  if (node >= N) return;
  bool act = lane<40;
  int l40 = act ? lane : 0;
  float erv = er[node];
  int beg = row_ptr[node], end = row_ptr[node+1];
  int deg = end - beg;
  int sv = (beg + lane < end) ? csr_src[beg+lane] : 0;
  float acc=0.f, denom=0.f;
  int nmain = deg > 64 ? 64 : deg;
  int i = 0;
  for (; i+4 <= nmain; i+=4){
    int s0=__shfl(sv,i+0), s1=__shfl(sv,i+1), s2=__shfl(sv,i+2), s3=__shfl(sv,i+3);
    float e0=el[s0], e1=el[s1], e2=el[s2], e3=el[s3];
    unsigned short f0=Fb[(size_t)s0*40+l40], f1=Fb[(size_t)s1*40+l40];
    unsigned short f2=Fb[(size_t)s2*40+l40], f3=Fb[(size_t)s3*40+l40];
    float x;
    x=e0+erv; x=x>0.f?x:0.2f*x; x=__expf(x); denom+=x; acc=fmaf(x,__uint_as_float(((uint32)f0)<<16),acc);
    x=e1+erv; x=x>0.f?x:0.2f*x; x=__expf(x); denom+=x; acc=fmaf(x,__uint_as_float(((uint32)f1)<<16),acc);
    x=e2+erv; x=x>0.f?x:0.2f*x; x=__expf(x); denom+=x; acc=fmaf(x,__uint_as_float(((uint32)f2)<<16),acc);
    x=e3+erv; x=x>0.f?x:0.2f*x; x=__expf(x); denom+=x; acc=fmaf(x,__uint_as_float(((uint32)f3)<<16),acc);
  }
  for (; i<nmain; i++){
    int s=__shfl(sv,i);
    float x=el[s]+erv; x=x>0.f?x:0.2f*x; x=__expf(x);
    unsigned short f=Fb[(size_t)s*40+l40];
    denom+=x; acc=fmaf(x,__uint_as_float(((uint32)f)<<16),acc);
  }
  if (deg > 64){
    for (int e=beg+64; e<end; e++){
      int s=csr_src[e];
      float x=el[s]+erv; x=x>0.f?x:0.2f*x; x=__expf(x);
      unsigned short f=Fb[(size_t)s*40+l40];
      denom+=x; acc=fmaf(x,__uint_as_float(((uint32)f)<<16),acc);
    }
  }
  float logit = acc/denom;
  float m = act ? logit : -INFINITY;
  for (int off=32; off; off>>=1) m = fmaxf(m, __shfl_xor(m, off));
  float ex = act ? expf(logit - m) : 0.f;
  float ssum = ex;
  for (int off=32; off; off>>=1) ssum += __shfl_xor(ssum, off);
  if (act) out[(size_t)node*40 + lane] = logit - m - logf(ssum);
}

extern "C" void kernel_launch(void* const* d_in, const int* in_sizes, int n_in,
                              void* d_out, int out_size, void* d_ws, size_t ws_size,
                              hipStream_t stream){
  const float* inputs = (const float*)d_in[0];
  const float* W0  = (const float*)d_in[1];
  const float* al0 = (const float*)d_in[2];
  const float* ar0 = (const float*)d_in[3];
  const float* W1  = (const float*)d_in[4];
  const float* al1 = (const float*)d_in[5];
  const float* ar1 = (const float*)d_in[6];
  const float* W2  = (const float*)d_in[7];
  const float* al2 = (const float*)d_in[8];
  const float* ar2 = (const float*)d_in[9];
  const int* src = (const int*)d_in[10];
  const int* dst = (const int*)d_in[11];
  int N = in_sizes[0]/128;
  int E = in_sizes[10];
  int NB = (N + (1<<BKT_SHIFT) - 1) >> BKT_SHIFT;

  char* p = (char*)d_ws;
  auto carve = [&](size_t bytes)->char*{ char* q=p; p += ((bytes+255)/256)*256; return q; };
  unsigned short* Fb   = (unsigned short*)carve((size_t)N*128*2);
  unsigned short* Fb40 = (unsigned short*)carve((size_t)N*40*2);
  float* bufH = (float*)carve((size_t)N*128*4);     // fp32 hidden; pairs alias this during CSR build
  float* el  = (float*)carve((size_t)N*4*4);
  float* er  = (float*)carve((size_t)N*4*4);
  float* el2 = (float*)carve((size_t)N*4);
  float* er2 = (float*)carve((size_t)N*4);
  // contiguous zero-init region: deg + subcnt + ovf_cnt
  char* zbase = p;
  int* deg     = (int*)carve((size_t)N*4);
  int* subcnt  = (int*)carve((size_t)NB*SUBS*4);
  int* ovf_cnt = (int*)carve(256);
  size_t zbytes = (size_t)(p - zbase);
  int* row_ptr = (int*)carve((size_t)(N+1)*4);
  int* cursor  = (int*)carve((size_t)N*4);
  int* partials= (int*)carve(128*4);
  int* csr_src = (int*)carve((size_t)E*4);

  uint2* pairs = (uint2*)bufH;                       // 196*4*4096*8 = 25.7 MB < 51.2 MB
  uint2* ovf   = pairs + (size_t)NB*SUBS*SUBCAP;

  hipMemsetAsync(zbase, 0, zbytes, stream);
  int nchunk = (N+1023)/1024;
  k_bucket  <<<(E+1023)/1024, 256, 0, stream>>>(src, dst, deg, subcnt, pairs, ovf_cnt, ovf, E);
  k_scanA   <<<nchunk, 256, 0, stream>>>(deg, partials, N);
  k_scanB   <<<1, 128, 0, stream>>>(partials, nchunk, row_ptr, N);
  k_scanC   <<<nchunk, 1024, 0, stream>>>(deg, partials, row_ptr, cursor, N);
  k_build   <<<NB, 1024, 0, stream>>>(subcnt, pairs, cursor, csr_src);
  k_overflow<<<1, 256, 0, stream>>>(ovf_cnt, ovf, cursor, csr_src);

  int gRows = (N+63)/64;
  int gWave = (N+3)/4;
  // layer 0
  k_gemm128<<<gRows,256,0,stream>>>(inputs, W0, al0, ar0, Fb, el, er, N);
  k_agg128 <<<gWave,256,0,stream>>>((const uint32*)Fb, el, er, row_ptr, csr_src, bufH, N);
  // layer 1
  k_gemm128<<<gRows,256,0,stream>>>(bufH, W1, al1, ar1, Fb, el, er, N);
  k_agg128 <<<gWave,256,0,stream>>>((const uint32*)Fb, el, er, row_ptr, csr_src, bufH, N);
  // layer 2
  k_gemm40 <<<gWave,256,0,stream>>>(bufH, W2, al2, ar2, Fb40, el2, er2, N);
  k_agg40  <<<gWave,256,0,stream>>>(Fb40, el2, er2, row_ptr, csr_src, (float*)d_out, N);
}

// Round 4
// 482.613 us; speedup vs baseline: 2.1819x; 2.1819x over previous
//
#include <hip/hip_runtime.h>
#include <math.h>

typedef unsigned int uint32;

__device__ inline uint32 bf16rn(float x){
  uint32 b = __float_as_uint(x);
  return (b + 0x7fffu + ((b>>16)&1u)) >> 16;
}
__device__ inline float bf16lo(uint32 v){ return __uint_as_float(v<<16); }
__device__ inline float bf16hi(uint32 v){ return __uint_as_float(v & 0xffff0000u); }

#define BKT_SHIFT 9            // 512 nodes per bucket
#define BKTCAP 12288           // per-bucket record capacity (mean ~8.7k, 16 sigma headroom)
#define PCHUNK 8192            // edges per partition block

// ---------------- pass 1: LDS-staged bucket partition ----------------
// record = src | (dst_local << 22)   (src < 2^22, dst_local < 512)
__global__ __launch_bounds__(256) void k_partition(const int* __restrict__ src, const int* __restrict__ dst,
                        int* __restrict__ bkt_cursor, uint32* __restrict__ pairs, int E){
  __shared__ int cnt[512];
  __shared__ int base[512];
  int t = threadIdx.x;
  int blockBase = blockIdx.x * PCHUNK;
  for (int i=t; i<512; i+=256) cnt[i]=0;
  __syncthreads();
  // phase A: LDS histogram of this block's edges
  #pragma unroll
  for (int i=0; i<PCHUNK/1024; i++){
    int e0 = blockBase + (i*256 + t)*4;
    if (e0+3 < E){
      int4 d4 = *(const int4*)&dst[e0];
      atomicAdd(&cnt[d4.x>>BKT_SHIFT],1);
      atomicAdd(&cnt[d4.y>>BKT_SHIFT],1);
      atomicAdd(&cnt[d4.z>>BKT_SHIFT],1);
      atomicAdd(&cnt[d4.w>>BKT_SHIFT],1);
    } else {
      for (int e=e0; e<E && e<e0+4; e++) atomicAdd(&cnt[dst[e]>>BKT_SHIFT],1);
    }
  }
  __syncthreads();
  // phase B: reserve block-private segments (196 global atomics per block)
  for (int i=t; i<512; i+=256){
    int c = cnt[i];
    base[i] = c ? atomicAdd(&bkt_cursor[i], c) : 0;
    cnt[i] = 0;
  }
  __syncthreads();
  // phase C: scatter packed records to block-private fronts
  #pragma unroll
  for (int i=0; i<PCHUNK/1024; i++){
    int e0 = blockBase + (i*256 + t)*4;
    if (e0+3 < E){
      int4 s4 = *(const int4*)&src[e0];
      int4 d4 = *(const int4*)&dst[e0];
      int bx, pos;
      bx=d4.x>>BKT_SHIFT; pos=base[bx]+atomicAdd(&cnt[bx],1); if(pos<BKTCAP) pairs[(size_t)bx*BKTCAP+pos]=(uint32)s4.x|((uint32)(d4.x&511)<<22);
      bx=d4.y>>BKT_SHIFT; pos=base[bx]+atomicAdd(&cnt[bx],1); if(pos<BKTCAP) pairs[(size_t)bx*BKTCAP+pos]=(uint32)s4.y|((uint32)(d4.y&511)<<22);
      bx=d4.z>>BKT_SHIFT; pos=base[bx]+atomicAdd(&cnt[bx],1); if(pos<BKTCAP) pairs[(size_t)bx*BKTCAP+pos]=(uint32)s4.z|((uint32)(d4.z&511)<<22);
      bx=d4.w>>BKT_SHIFT; pos=base[bx]+atomicAdd(&cnt[bx],1); if(pos<BKTCAP) pairs[(size_t)bx*BKTCAP+pos]=(uint32)s4.w|((uint32)(d4.w&511)<<22);
    } else {
      for (int e=e0; e<E && e<e0+4; e++){
        int s=src[e], d=dst[e];
        int bx=d>>BKT_SHIFT; int pos=base[bx]+atomicAdd(&cnt[bx],1);
        if(pos<BKTCAP) pairs[(size_t)bx*BKTCAP+pos]=(uint32)s|((uint32)(d&511)<<22);
      }
    }
  }
}

// ---------------- pass 2: scan bucket totals ----------------
__global__ __launch_bounds__(512) void k_scanbkt(const int* __restrict__ bkt_cursor, int nb,
                      int* __restrict__ bucket_base, int* __restrict__ row_ptr, int N){
  __shared__ int sc[512];
  int t = threadIdx.x;
  int v = (t<nb) ? min(bkt_cursor[t], BKTCAP) : 0;
  sc[t]=v; __syncthreads();
  int x=v;
  for (int off=1; off<512; off<<=1){
    int y=(t>=off)? sc[t-off]:0;
    __syncthreads();
    x+=y; sc[t]=x;
    __syncthreads();
  }
  if (t<nb) bucket_base[t] = x - v;
  if (t==511) row_ptr[N] = x;
}

// ---------------- pass 3: per-bucket CSR build (zero global atomics) ----------------
__global__ __launch_bounds__(1024) void k_build(const int* __restrict__ bkt_cursor,
                        const int* __restrict__ bucket_base, const uint32* __restrict__ pairs,
                        int* __restrict__ row_ptr, int* __restrict__ csr_src, int N){
  __shared__ int hist[512];
  __shared__ int sc[512];
  __shared__ int cur[512];
  int b = blockIdx.x;
  int t = threadIdx.x;
  int cnt = bkt_cursor[b]; if (cnt > BKTCAP) cnt = BKTCAP;
  int base = bucket_base[b];
  const uint32* p = pairs + (size_t)b*BKTCAP;
  if (t<512) hist[t]=0;
  __syncthreads();
  for (int i=t; i<cnt; i+=1024) atomicAdd(&hist[p[i]>>22], 1);
  __syncthreads();
  int v = (t<512)? hist[t] : 0;
  if (t<512) sc[t]=v;
  __syncthreads();
  int x=v;
  for (int off=1; off<512; off<<=1){
    int y = (t<512 && t>=off)? sc[t-off] : 0;
    __syncthreads();
    if (t<512){ x+=y; sc[t]=x; }
    __syncthreads();
  }
  if (t<512){
    int excl = x - v;
    int gnode = (b<<BKT_SHIFT) + t;
    if (gnode < N) row_ptr[gnode] = base + excl;
    cur[t] = excl;
  }
  __syncthreads();
  for (int i=t; i<cnt; i+=1024){
    uint32 e = p[i];
    int pos = atomicAdd(&cur[e>>22], 1);
    csr_src[base + pos] = (int)(e & 0x3FFFFFu);
  }
}

// ---------------- GEMM [N,128]x[128,128] -> bf16 F + fused el/er ----------------
__global__ __launch_bounds__(256) void k_gemm128(const float* __restrict__ A, const float* __restrict__ W,
                                                 const float* __restrict__ al, const float* __restrict__ ar,
                                                 unsigned short* __restrict__ Fb,
                                                 float* __restrict__ el, float* __restrict__ er, int N){
  __shared__ float hs[32][68];
  __shared__ float ws[32][128];
  int t = threadIdx.x;
  int rowBase = blockIdx.x*64;
  int rg8 = (t>>5)*8;
  int cq  = (t&31)*4;
  float acc[8][4] = {};
  for (int kc=0; kc<128; kc+=32){
    {
      int row = t>>2; int kk = (t&3)*8;
      int grow = rowBase+row;
      float4 v0, v1;
      if (grow < N){
        v0 = *(const float4*)&A[(size_t)grow*128 + kc + kk];
        v1 = *(const float4*)&A[(size_t)grow*128 + kc + kk + 4];
      } else { v0 = make_float4(0,0,0,0); v1 = v0; }
      hs[kk+0][row]=v0.x; hs[kk+1][row]=v0.y; hs[kk+2][row]=v0.z; hs[kk+3][row]=v0.w;
      hs[kk+4][row]=v1.x; hs[kk+5][row]=v1.y; hs[kk+6][row]=v1.z; hs[kk+7][row]=v1.w;
    }
    {
      int k = t>>3; int c0 = (t&7)*16;
      const float4* wp = (const float4*)&W[(size_t)(kc+k)*128 + c0];
      float4 w0=wp[0], w1=wp[1], w2=wp[2], w3=wp[3];
      *(float4*)&ws[k][c0+ 0]=w0; *(float4*)&ws[k][c0+ 4]=w1;
      *(float4*)&ws[k][c0+ 8]=w2; *(float4*)&ws[k][c0+12]=w3;
    }
    __syncthreads();
    #pragma unroll
    for (int k=0;k<32;k++){
      float4 bv  = *(const float4*)&ws[k][cq];
      float4 av0 = *(const float4*)&hs[k][rg8];
      float4 av1 = *(const float4*)&hs[k][rg8+4];
      float a8[8] = {av0.x,av0.y,av0.z,av0.w,av1.x,av1.y,av1.z,av1.w};
      float b4[4] = {bv.x,bv.y,bv.z,bv.w};
      #pragma unroll
      for (int r=0;r<8;r++)
        #pragma unroll
        for (int c=0;c<4;c++)
          acc[r][c] = fmaf(a8[r], b4[c], acc[r][c]);
    }
    __syncthreads();
  }
  float al4[4], ar4[4];
  #pragma unroll
  for (int i=0;i<4;i++){ al4[i]=al[cq+i]; ar4[i]=ar[cq+i]; }
  int c = t&31;
  int h = c>>3;
  int rowTop = rowBase + rg8;
  #pragma unroll
  for (int r=0;r<8;r++){
    int row = rowTop + r;
    if (row < N){
      uint32 u0 = bf16rn(acc[r][0]) | (bf16rn(acc[r][1])<<16);
      uint32 u1 = bf16rn(acc[r][2]) | (bf16rn(acc[r][3])<<16);
      *(uint2*)(Fb + (size_t)row*128 + cq) = make_uint2(u0,u1);
    }
    float pl = acc[r][0]*al4[0]+acc[r][1]*al4[1]+acc[r][2]*al4[2]+acc[r][3]*al4[3];
    float pr = acc[r][0]*ar4[0]+acc[r][1]*ar4[1]+acc[r][2]*ar4[2]+acc[r][3]*ar4[3];
    pl += __shfl_xor(pl,1); pr += __shfl_xor(pr,1);
    pl += __shfl_xor(pl,2); pr += __shfl_xor(pr,2);
    pl += __shfl_xor(pl,4); pr += __shfl_xor(pr,4);
    if ((c&7)==0 && row < N){ el[(size_t)row*4+h]=pl; er[(size_t)row*4+h]=pr; }
  }
}

// ---------------- fused edge-softmax + aggregation (H=4,D=32), bf16 gather ----------------
#define AGG_STEP(sY) { int s_=(sY); \
    float x_=el[(size_t)s_*4+h]+erv; x_=x_>0.f?x_:0.2f*x_; x_=__expf(x_); \
    uint32 v_=Fu[(size_t)s_*64+lane]; \
    denom+=x_; acc0=fmaf(x_,bf16lo(v_),acc0); acc1=fmaf(x_,bf16hi(v_),acc1); }

__global__ __launch_bounds__(256) void k_agg128(const uint32* __restrict__ Fu, const float* __restrict__ el,
                         const float* __restrict__ er, const int* __restrict__ row_ptr,
                         const int* __restrict__ csr_src, float* __restrict__ out, int N){
  int node = (blockIdx.x*blockDim.x + threadIdx.x)>>6;
  int lane = threadIdx.x & 63;
  if (node >= N) return;
  int h = lane>>4;
  float erv = er[(size_t)node*4+h];
  int beg = row_ptr[node], end = row_ptr[node+1];
  int deg = end - beg;
  int sv = (beg + lane < end) ? csr_src[beg+lane] : 0;
  float acc0=0.f, acc1=0.f, denom=0.f;
  int nmain = deg > 64 ? 64 : deg;
  int i = 0;
  for (; i+8 <= nmain; i+=8){
    int s0=__shfl(sv,i+0), s1=__shfl(sv,i+1), s2=__shfl(sv,i+2), s3=__shfl(sv,i+3);
    int s4=__shfl(sv,i+4), s5=__shfl(sv,i+5), s6=__shfl(sv,i+6), s7=__shfl(sv,i+7);
    AGG_STEP(s0); AGG_STEP(s1); AGG_STEP(s2); AGG_STEP(s3);
    AGG_STEP(s4); AGG_STEP(s5); AGG_STEP(s6); AGG_STEP(s7);
  }
  for (; i<nmain; i++){ int s=__shfl(sv,i); AGG_STEP(s); }
  if (deg > 64){
    for (int e=beg+64; e<end; e++){ int s=csr_src[e]; AGG_STEP(s); }
  }
  float inv = 1.0f/denom;
  float o0 = acc0*inv, o1 = acc1*inv;
  o0 = o0>0.f ? o0 : expm1f(o0);
  o1 = o1>0.f ? o1 : expm1f(o1);
  *(float2*)&out[(size_t)node*128 + lane*2] = make_float2(o0,o1);
}

// ---------------- layer-2 GEMM [N,128]x[128,40] fused with el2/er2, bf16 F ----------------
__global__ __launch_bounds__(256) void k_gemm40(const float* __restrict__ A, const float* __restrict__ W,
                        const float* __restrict__ al, const float* __restrict__ ar,
                        unsigned short* __restrict__ Fb, float* __restrict__ el, float* __restrict__ er, int N){
  __shared__ float ws[5120];
  __shared__ float sal[64], sar[64];
  int t = threadIdx.x;
  for (int i=t; i<5120; i+=256) ws[i] = W[i];
  if (t<40){ sal[t]=al[t]; sar[t]=ar[t]; }
  else if (t<64){ sal[t]=0.f; sar[t]=0.f; }
  __syncthreads();
  int node = blockIdx.x*4 + (t>>6);
  int lane = t & 63;
  if (node >= N) return;
  int l40 = lane<40 ? lane : 0;
  const float* a = A + (size_t)node*128;
  float acc = 0.f;
  #pragma unroll
  for (int k=0;k<128;k+=4){
    float4 hv = *(const float4*)&a[k];
    acc = fmaf(hv.x, ws[(k+0)*40+l40], acc);
    acc = fmaf(hv.y, ws[(k+1)*40+l40], acc);
    acc = fmaf(hv.z, ws[(k+2)*40+l40], acc);
    acc = fmaf(hv.w, ws[(k+3)*40+l40], acc);
  }
  bool act = lane<40;
  float pl = act ? acc*sal[lane] : 0.f;
  float pr = act ? acc*sar[lane] : 0.f;
  for (int off=32; off; off>>=1){ pl += __shfl_xor(pl, off); pr += __shfl_xor(pr, off); }
  if (lane==0){ el[node]=pl; er[node]=pr; }
  if (act) Fb[(size_t)node*40 + lane] = (unsigned short)bf16rn(acc);
}

// ---------------- final aggregation (H=1,D=40) + log_softmax, bf16 gather ----------------
__global__ __launch_bounds__(256) void k_agg40(const unsigned short* __restrict__ Fb, const float* __restrict__ el,
                       const float* __restrict__ er, const int* __restrict__ row_ptr,
                       const int* __restrict__ csr_src, float* __restrict__ out, int N){
  int node = (blockIdx.x*blockDim.x + threadIdx.x)>>6;
  int lane = threadIdx.x & 63;
  if (node >= N) return;
  bool act = lane<40;
  int l40 = act ? lane : 0;
  float erv = er[node];
  int beg = row_ptr[node], end = row_ptr[node+1];
  int deg = end - beg;
  int sv = (beg + lane < end) ? csr_src[beg+lane] : 0;
  float acc=0.f, denom=0.f;
  int nmain = deg > 64 ? 64 : deg;
  int i = 0;
  for (; i+4 <= nmain; i+=4){
    int s0=__shfl(sv,i+0), s1=__shfl(sv,i+1), s2=__shfl(sv,i+2), s3=__shfl(sv,i+3);
    float e0=el[s0], e1=el[s1], e2=el[s2], e3=el[s3];
    unsigned short f0=Fb[(size_t)s0*40+l40], f1=Fb[(size_t)s1*40+l40];
    unsigned short f2=Fb[(size_t)s2*40+l40], f3=Fb[(size_t)s3*40+l40];
    float x;
    x=e0+erv; x=x>0.f?x:0.2f*x; x=__expf(x); denom+=x; acc=fmaf(x,__uint_as_float(((uint32)f0)<<16),acc);
    x=e1+erv; x=x>0.f?x:0.2f*x; x=__expf(x); denom+=x; acc=fmaf(x,__uint_as_float(((uint32)f1)<<16),acc);
    x=e2+erv; x=x>0.f?x:0.2f*x; x=__expf(x); denom+=x; acc=fmaf(x,__uint_as_float(((uint32)f2)<<16),acc);
    x=e3+erv; x=x>0.f?x:0.2f*x; x=__expf(x); denom+=x; acc=fmaf(x,__uint_as_float(((uint32)f3)<<16),acc);
  }
  for (; i<nmain; i++){
    int s=__shfl(sv,i);
    float x=el[s]+erv; x=x>0.f?x:0.2f*x; x=__expf(x);
    unsigned short f=Fb[(size_t)s*40+l40];
    denom+=x; acc=fmaf(x,__uint_as_float(((uint32)f)<<16),acc);
  }
  if (deg > 64){
    for (int e=beg+64; e<end; e++){
      int s=csr_src[e];
      float x=el[s]+erv; x=x>0.f?x:0.2f*x; x=__expf(x);
      unsigned short f=Fb[(size_t)s*40+l40];
      denom+=x; acc=fmaf(x,__uint_as_float(((uint32)f)<<16),acc);
    }
  }
  float logit = acc/denom;
  float m = act ? logit : -INFINITY;
  for (int off=32; off; off>>=1) m = fmaxf(m, __shfl_xor(m, off));
  float ex = act ? expf(logit - m) : 0.f;
  float ssum = ex;
  for (int off=32; off; off>>=1) ssum += __shfl_xor(ssum, off);
  if (act) out[(size_t)node*40 + lane] = logit - m - logf(ssum);
}

extern "C" void kernel_launch(void* const* d_in, const int* in_sizes, int n_in,
                              void* d_out, int out_size, void* d_ws, size_t ws_size,
                              hipStream_t stream){
  const float* inputs = (const float*)d_in[0];
  const float* W0  = (const float*)d_in[1];
  const float* al0 = (const float*)d_in[2];
  const float* ar0 = (const float*)d_in[3];
  const float* W1  = (const float*)d_in[4];
  const float* al1 = (const float*)d_in[5];
  const float* ar1 = (const float*)d_in[6];
  const float* W2  = (const float*)d_in[7];
  const float* al2 = (const float*)d_in[8];
  const float* ar2 = (const float*)d_in[9];
  const int* src = (const int*)d_in[10];
  const int* dst = (const int*)d_in[11];
  int N = in_sizes[0]/128;
  int E = in_sizes[10];
  int NB = (N + (1<<BKT_SHIFT) - 1) >> BKT_SHIFT;

  char* p = (char*)d_ws;
  auto carve = [&](size_t bytes)->char*{ char* q=p; p += ((bytes+255)/256)*256; return q; };
  unsigned short* Fb   = (unsigned short*)carve((size_t)N*128*2);
  unsigned short* Fb40 = (unsigned short*)carve((size_t)N*40*2);
  float* bufH = (float*)carve((size_t)N*128*4);     // fp32 hidden; pairs alias this during CSR build
  float* el  = (float*)carve((size_t)N*4*4);
  float* er  = (float*)carve((size_t)N*4*4);
  float* el2 = (float*)carve((size_t)N*4);
  float* er2 = (float*)carve((size_t)N*4);
  int* bkt_cursor  = (int*)carve((size_t)NB*4);     // zero-init
  int* bucket_base = (int*)carve((size_t)NB*4);
  int* row_ptr = (int*)carve((size_t)(N+1)*4);
  int* csr_src = (int*)carve((size_t)E*4);

  uint32* pairs = (uint32*)bufH;                    // NB*BKTCAP*4 = 9.6 MB < 51.2 MB

  hipMemsetAsync(bkt_cursor, 0, (size_t)NB*4, stream);
  int nPB = (E + PCHUNK - 1) / PCHUNK;
  k_partition<<<nPB, 256, 0, stream>>>(src, dst, bkt_cursor, pairs, E);
  k_scanbkt  <<<1, 512, 0, stream>>>(bkt_cursor, NB, bucket_base, row_ptr, N);
  k_build    <<<NB, 1024, 0, stream>>>(bkt_cursor, bucket_base, pairs, row_ptr, csr_src, N);

  int gRows = (N+63)/64;
  int gWave = (N+3)/4;
  // layer 0
  k_gemm128<<<gRows,256,0,stream>>>(inputs, W0, al0, ar0, Fb, el, er, N);
  k_agg128 <<<gWave,256,0,stream>>>((const uint32*)Fb, el, er, row_ptr, csr_src, bufH, N);
  // layer 1
  k_gemm128<<<gRows,256,0,stream>>>(bufH, W1, al1, ar1, Fb, el, er, N);
  k_agg128 <<<gWave,256,0,stream>>>((const uint32*)Fb, el, er, row_ptr, csr_src, bufH, N);
  // layer 2
  k_gemm40 <<<gWave,256,0,stream>>>(bufH, W2, al2, ar2, Fb40, el2, er2, N);
  k_agg40  <<<gWave,256,0,stream>>>(Fb40, el2, er2, row_ptr, csr_src, (float*)d_out, N);
}

// Round 5
// 412.381 us; speedup vs baseline: 2.5535x; 1.1703x over previous
//
#include <hip/hip_runtime.h>
#include <math.h>

typedef unsigned int uint32;

__device__ inline uint32 bf16rn(float x){
  uint32 b = __float_as_uint(x);
  return (b + 0x7fffu + ((b>>16)&1u)) >> 16;
}
__device__ inline float bf16lo(uint32 v){ return __uint_as_float(v<<16); }
__device__ inline float bf16hi(uint32 v){ return __uint_as_float(v & 0xffff0000u); }

#define BKT_SHIFT 9            // 512 nodes per bucket
#define BKTCAP 12288           // per-bucket record capacity
#define PCHUNK 8192            // edges per partition block

// ---------------- pass 1: LDS-staged bucket partition ----------------
__global__ __launch_bounds__(256) void k_partition(const int* __restrict__ src, const int* __restrict__ dst,
                        int* __restrict__ bkt_cursor, uint32* __restrict__ pairs, int E){
  __shared__ int cnt[512];
  __shared__ int base[512];
  int t = threadIdx.x;
  int blockBase = blockIdx.x * PCHUNK;
  for (int i=t; i<512; i+=256) cnt[i]=0;
  __syncthreads();
  #pragma unroll
  for (int i=0; i<PCHUNK/1024; i++){
    int e0 = blockBase + (i*256 + t)*4;
    if (e0+3 < E){
      int4 d4 = *(const int4*)&dst[e0];
      atomicAdd(&cnt[d4.x>>BKT_SHIFT],1);
      atomicAdd(&cnt[d4.y>>BKT_SHIFT],1);
      atomicAdd(&cnt[d4.z>>BKT_SHIFT],1);
      atomicAdd(&cnt[d4.w>>BKT_SHIFT],1);
    } else {
      for (int e=e0; e<E && e<e0+4; e++) atomicAdd(&cnt[dst[e]>>BKT_SHIFT],1);
    }
  }
  __syncthreads();
  for (int i=t; i<512; i+=256){
    int c = cnt[i];
    base[i] = c ? atomicAdd(&bkt_cursor[i], c) : 0;
    cnt[i] = 0;
  }
  __syncthreads();
  #pragma unroll
  for (int i=0; i<PCHUNK/1024; i++){
    int e0 = blockBase + (i*256 + t)*4;
    if (e0+3 < E){
      int4 s4 = *(const int4*)&src[e0];
      int4 d4 = *(const int4*)&dst[e0];
      int bx, pos;
      bx=d4.x>>BKT_SHIFT; pos=base[bx]+atomicAdd(&cnt[bx],1); if(pos<BKTCAP) pairs[(size_t)bx*BKTCAP+pos]=(uint32)s4.x|((uint32)(d4.x&511)<<22);
      bx=d4.y>>BKT_SHIFT; pos=base[bx]+atomicAdd(&cnt[bx],1); if(pos<BKTCAP) pairs[(size_t)bx*BKTCAP+pos]=(uint32)s4.y|((uint32)(d4.y&511)<<22);
      bx=d4.z>>BKT_SHIFT; pos=base[bx]+atomicAdd(&cnt[bx],1); if(pos<BKTCAP) pairs[(size_t)bx*BKTCAP+pos]=(uint32)s4.z|((uint32)(d4.z&511)<<22);
      bx=d4.w>>BKT_SHIFT; pos=base[bx]+atomicAdd(&cnt[bx],1); if(pos<BKTCAP) pairs[(size_t)bx*BKTCAP+pos]=(uint32)s4.w|((uint32)(d4.w&511)<<22);
    } else {
      for (int e=e0; e<E && e<e0+4; e++){
        int s=src[e], d=dst[e];
        int bx=d>>BKT_SHIFT; int pos=base[bx]+atomicAdd(&cnt[bx],1);
        if(pos<BKTCAP) pairs[(size_t)bx*BKTCAP+pos]=(uint32)s|((uint32)(d&511)<<22);
      }
    }
  }
}

// ---------------- pass 2: scan bucket totals ----------------
__global__ __launch_bounds__(512) void k_scanbkt(const int* __restrict__ bkt_cursor, int nb,
                      int* __restrict__ bucket_base, int* __restrict__ row_ptr, int N){
  __shared__ int sc[512];
  int t = threadIdx.x;
  int v = (t<nb) ? min(bkt_cursor[t], BKTCAP) : 0;
  sc[t]=v; __syncthreads();
  int x=v;
  for (int off=1; off<512; off<<=1){
    int y=(t>=off)? sc[t-off]:0;
    __syncthreads();
    x+=y; sc[t]=x;
    __syncthreads();
  }
  if (t<nb) bucket_base[t] = x - v;
  if (t==511) row_ptr[N] = x;
}

// ---------------- pass 3: per-bucket CSR build ----------------
__global__ __launch_bounds__(1024) void k_build(const int* __restrict__ bkt_cursor,
                        const int* __restrict__ bucket_base, const uint32* __restrict__ pairs,
                        int* __restrict__ row_ptr, int* __restrict__ csr_src, int N){
  __shared__ int hist[512];
  __shared__ int sc[512];
  __shared__ int cur[512];
  int b = blockIdx.x;
  int t = threadIdx.x;
  int cnt = bkt_cursor[b]; if (cnt > BKTCAP) cnt = BKTCAP;
  int base = bucket_base[b];
  const uint32* p = pairs + (size_t)b*BKTCAP;
  if (t<512) hist[t]=0;
  __syncthreads();
  for (int i=t; i<cnt; i+=1024) atomicAdd(&hist[p[i]>>22], 1);
  __syncthreads();
  int v = (t<512)? hist[t] : 0;
  if (t<512) sc[t]=v;
  __syncthreads();
  int x=v;
  for (int off=1; off<512; off<<=1){
    int y = (t<512 && t>=off)? sc[t-off] : 0;
    __syncthreads();
    if (t<512){ x+=y; sc[t]=x; }
    __syncthreads();
  }
  if (t<512){
    int excl = x - v;
    int gnode = (b<<BKT_SHIFT) + t;
    if (gnode < N) row_ptr[gnode] = base + excl;
    cur[t] = excl;
  }
  __syncthreads();
  for (int i=t; i<cnt; i+=1024){
    uint32 e = p[i];
    int pos = atomicAdd(&cur[e>>22], 1);
    csr_src[base + pos] = (int)(e & 0x3FFFFFu);
  }
}

// ---------------- GEMM [N,128]x[128,128] -> bf16 F + fused el/er ----------------
__global__ __launch_bounds__(256) void k_gemm128(const float* __restrict__ A, const float* __restrict__ W,
                                                 const float* __restrict__ al, const float* __restrict__ ar,
                                                 unsigned short* __restrict__ Fb,
                                                 float* __restrict__ el, float* __restrict__ er, int N){
  __shared__ float hs[32][68];
  __shared__ float ws[32][128];
  int t = threadIdx.x;
  int rowBase = blockIdx.x*64;
  int rg8 = (t>>5)*8;
  int cq  = (t&31)*4;
  float acc[8][4] = {};
  for (int kc=0; kc<128; kc+=32){
    {
      int row = t>>2; int kk = (t&3)*8;
      int grow = rowBase+row;
      float4 v0, v1;
      if (grow < N){
        v0 = *(const float4*)&A[(size_t)grow*128 + kc + kk];
        v1 = *(const float4*)&A[(size_t)grow*128 + kc + kk + 4];
      } else { v0 = make_float4(0,0,0,0); v1 = v0; }
      hs[kk+0][row]=v0.x; hs[kk+1][row]=v0.y; hs[kk+2][row]=v0.z; hs[kk+3][row]=v0.w;
      hs[kk+4][row]=v1.x; hs[kk+5][row]=v1.y; hs[kk+6][row]=v1.z; hs[kk+7][row]=v1.w;
    }
    {
      int k = t>>3; int c0 = (t&7)*16;
      const float4* wp = (const float4*)&W[(size_t)(kc+k)*128 + c0];
      float4 w0=wp[0], w1=wp[1], w2=wp[2], w3=wp[3];
      *(float4*)&ws[k][c0+ 0]=w0; *(float4*)&ws[k][c0+ 4]=w1;
      *(float4*)&ws[k][c0+ 8]=w2; *(float4*)&ws[k][c0+12]=w3;
    }
    __syncthreads();
    #pragma unroll
    for (int k=0;k<32;k++){
      float4 bv  = *(const float4*)&ws[k][cq];
      float4 av0 = *(const float4*)&hs[k][rg8];
      float4 av1 = *(const float4*)&hs[k][rg8+4];
      float a8[8] = {av0.x,av0.y,av0.z,av0.w,av1.x,av1.y,av1.z,av1.w};
      float b4[4] = {bv.x,bv.y,bv.z,bv.w};
      #pragma unroll
      for (int r=0;r<8;r++)
        #pragma unroll
        for (int c=0;c<4;c++)
          acc[r][c] = fmaf(a8[r], b4[c], acc[r][c]);
    }
    __syncthreads();
  }
  float al4[4], ar4[4];
  #pragma unroll
  for (int i=0;i<4;i++){ al4[i]=al[cq+i]; ar4[i]=ar[cq+i]; }
  int c = t&31;
  int h = c>>3;
  int rowTop = rowBase + rg8;
  #pragma unroll
  for (int r=0;r<8;r++){
    int row = rowTop + r;
    if (row < N){
      uint32 u0 = bf16rn(acc[r][0]) | (bf16rn(acc[r][1])<<16);
      uint32 u1 = bf16rn(acc[r][2]) | (bf16rn(acc[r][3])<<16);
      *(uint2*)(Fb + (size_t)row*128 + cq) = make_uint2(u0,u1);
    }
    float pl = acc[r][0]*al4[0]+acc[r][1]*al4[1]+acc[r][2]*al4[2]+acc[r][3]*al4[3];
    float pr = acc[r][0]*ar4[0]+acc[r][1]*ar4[1]+acc[r][2]*ar4[2]+acc[r][3]*ar4[3];
    pl += __shfl_xor(pl,1); pr += __shfl_xor(pr,1);
    pl += __shfl_xor(pl,2); pr += __shfl_xor(pr,2);
    pl += __shfl_xor(pl,4); pr += __shfl_xor(pr,4);
    if ((c&7)==0 && row < N){ el[(size_t)row*4+h]=pl; er[(size_t)row*4+h]=pr; }
  }
}

// ---------------- fused edge-softmax + aggregation (H=4,D=32), bf16 gather ----------------
#define AGG_STEP(sY) { int s_=(sY); \
    float x_=el[(size_t)s_*4+h]+erv; x_=x_>0.f?x_:0.2f*x_; x_=__expf(x_); \
    uint32 v_=Fu[(size_t)s_*64+lane]; \
    denom+=x_; acc0=fmaf(x_,bf16lo(v_),acc0); acc1=fmaf(x_,bf16hi(v_),acc1); }

__global__ __launch_bounds__(256) void k_agg128(const uint32* __restrict__ Fu, const float* __restrict__ el,
                         const float* __restrict__ er, const int* __restrict__ row_ptr,
                         const int* __restrict__ csr_src, float* __restrict__ out, int N){
  int node = (blockIdx.x*blockDim.x + threadIdx.x)>>6;
  int lane = threadIdx.x & 63;
  if (node >= N) return;
  int h = lane>>4;
  float erv = er[(size_t)node*4+h];
  int beg = row_ptr[node], end = row_ptr[node+1];
  int deg = end - beg;
  int sv = (beg + lane < end) ? csr_src[beg+lane] : 0;
  float acc0=0.f, acc1=0.f, denom=0.f;
  int nmain = deg > 64 ? 64 : deg;
  int i = 0;
  for (; i+8 <= nmain; i+=8){
    int s0=__shfl(sv,i+0), s1=__shfl(sv,i+1), s2=__shfl(sv,i+2), s3=__shfl(sv,i+3);
    int s4=__shfl(sv,i+4), s5=__shfl(sv,i+5), s6=__shfl(sv,i+6), s7=__shfl(sv,i+7);
    AGG_STEP(s0); AGG_STEP(s1); AGG_STEP(s2); AGG_STEP(s3);
    AGG_STEP(s4); AGG_STEP(s5); AGG_STEP(s6); AGG_STEP(s7);
  }
  for (; i<nmain; i++){ int s=__shfl(sv,i); AGG_STEP(s); }
  if (deg > 64){
    for (int e=beg+64; e<end; e++){ int s=csr_src[e]; AGG_STEP(s); }
  }
  float inv = 1.0f/denom;
  float o0 = acc0*inv, o1 = acc1*inv;
  o0 = o0>0.f ? o0 : expm1f(o0);
  o1 = o1>0.f ? o1 : expm1f(o1);
  *(float2*)&out[(size_t)node*128 + lane*2] = make_float2(o0,o1);
}

// ---------------- layer-2: tiled GEMM [N,128]x[128,40+2] -> bf16 Fb40, el2, er2 ----------------
// 128 rows/block, 256 threads, thread = 4 rows x 6 cols. Cols 40/41 are W2@al2 / W2@ar2.
__global__ __launch_bounds__(256) void k_gemm42(const float* __restrict__ A, const float* __restrict__ W,
                        const float* __restrict__ al, const float* __restrict__ ar,
                        unsigned short* __restrict__ Fb, float* __restrict__ el, float* __restrict__ er, int N){
  __shared__ float wfull[128*48];   // [k][48]: cols 0..39=W2, 40=wl, 41=wr, 42..47=0
  __shared__ float hs[32][132];     // transposed A chunk
  int t = threadIdx.x;
  int rowBase = blockIdx.x*128;
  // stage W2 cols 0..39 (float4; 40%4==0 so no row crossing)
  for (int i=t; i<1280; i+=256){
    float4 v = *(const float4*)&W[i*4];
    int g = i*4;
    *(float4*)&wfull[(g/40)*48 + (g%40)] = v;
  }
  // wl/wr + zero padding
  {
    int k = t & 127;
    const float* wrow = W + k*40;
    const float* a = (t < 128) ? al : ar;
    float s = 0.f;
    #pragma unroll
    for (int c=0;c<40;c++) s += wrow[c]*a[c];
    if (t < 128){
      wfull[k*48+40] = s;
      wfull[k*48+42] = 0.f; wfull[k*48+43] = 0.f; wfull[k*48+44] = 0.f;
    } else {
      wfull[k*48+41] = s;
      wfull[k*48+45] = 0.f; wfull[k*48+46] = 0.f; wfull[k*48+47] = 0.f;
    }
  }
  int c0 = (t&7)*6;
  int r0 = (t>>3)*4;
  float acc[4][6] = {};
  for (int kc=0; kc<128; kc+=32){
    {
      int row = t>>1; int kk0 = (t&1)*16;
      int grow = rowBase + row;
      #pragma unroll
      for (int j=0;j<4;j++){
        float4 v = (grow<N) ? *(const float4*)&A[(size_t)grow*128 + kc + kk0 + 4*j] : make_float4(0,0,0,0);
        hs[kk0+4*j+0][row]=v.x; hs[kk0+4*j+1][row]=v.y; hs[kk0+4*j+2][row]=v.z; hs[kk0+4*j+3][row]=v.w;
      }
    }
    __syncthreads();
    #pragma unroll
    for (int k=0;k<32;k++){
      float4 av = *(const float4*)&hs[k][r0];
      const float* wp = &wfull[(kc+k)*48 + c0];
      float2 b01 = *(const float2*)&wp[0];
      float2 b23 = *(const float2*)&wp[2];
      float2 b45 = *(const float2*)&wp[4];
      float a4[4] = {av.x,av.y,av.z,av.w};
      float b6[6] = {b01.x,b01.y,b23.x,b23.y,b45.x,b45.y};
      #pragma unroll
      for (int r=0;r<4;r++)
        #pragma unroll
        for (int c=0;c<6;c++)
          acc[r][c] = fmaf(a4[r], b6[c], acc[r][c]);
    }
    __syncthreads();
  }
  // epilogue
  #pragma unroll
  for (int r=0;r<4;r++){
    int row = rowBase + r0 + r;
    if (row >= N) break;
    if (c0 < 40){
      #pragma unroll
      for (int j=0;j<6;j+=2){
        int col = c0 + j;
        if (col < 40){
          uint32 u = bf16rn(acc[r][j]) | (bf16rn(acc[r][j+1])<<16);
          *(uint32*)(Fb + (size_t)row*40 + col) = u;
        }
      }
      if (c0 == 36){ el[row] = acc[r][4]; er[row] = acc[r][5]; }
    }
  }
}

// ---------------- final aggregation (H=1,D=40) + log_softmax, bf16 gather ----------------
__global__ __launch_bounds__(256) void k_agg40(const unsigned short* __restrict__ Fb, const float* __restrict__ el,
                       const float* __restrict__ er, const int* __restrict__ row_ptr,
                       const int* __restrict__ csr_src, float* __restrict__ out, int N){
  int node = (blockIdx.x*blockDim.x + threadIdx.x)>>6;
  int lane = threadIdx.x & 63;
  if (node >= N) return;
  bool act = lane<40;
  int l40 = act ? lane : 0;
  float erv = er[node];
  int beg = row_ptr[node], end = row_ptr[node+1];
  int deg = end - beg;
  int sv = (beg + lane < end) ? csr_src[beg+lane] : 0;
  float acc=0.f, denom=0.f;
  int nmain = deg > 64 ? 64 : deg;
  int i = 0;
  for (; i+4 <= nmain; i+=4){
    int s0=__shfl(sv,i+0), s1=__shfl(sv,i+1), s2=__shfl(sv,i+2), s3=__shfl(sv,i+3);
    float e0=el[s0], e1=el[s1], e2=el[s2], e3=el[s3];
    unsigned short f0=Fb[(size_t)s0*40+l40], f1=Fb[(size_t)s1*40+l40];
    unsigned short f2=Fb[(size_t)s2*40+l40], f3=Fb[(size_t)s3*40+l40];
    float x;
    x=e0+erv; x=x>0.f?x:0.2f*x; x=__expf(x); denom+=x; acc=fmaf(x,__uint_as_float(((uint32)f0)<<16),acc);
    x=e1+erv; x=x>0.f?x:0.2f*x; x=__expf(x); denom+=x; acc=fmaf(x,__uint_as_float(((uint32)f1)<<16),acc);
    x=e2+erv; x=x>0.f?x:0.2f*x; x=__expf(x); denom+=x; acc=fmaf(x,__uint_as_float(((uint32)f2)<<16),acc);
    x=e3+erv; x=x>0.f?x:0.2f*x; x=__expf(x); denom+=x; acc=fmaf(x,__uint_as_float(((uint32)f3)<<16),acc);
  }
  for (; i<nmain; i++){
    int s=__shfl(sv,i);
    float x=el[s]+erv; x=x>0.f?x:0.2f*x; x=__expf(x);
    unsigned short f=Fb[(size_t)s*40+l40];
    denom+=x; acc=fmaf(x,__uint_as_float(((uint32)f)<<16),acc);
  }
  if (deg > 64){
    for (int e=beg+64; e<end; e++){
      int s=csr_src[e];
      float x=el[s]+erv; x=x>0.f?x:0.2f*x; x=__expf(x);
      unsigned short f=Fb[(size_t)s*40+l40];
      denom+=x; acc=fmaf(x,__uint_as_float(((uint32)f)<<16),acc);
    }
  }
  float logit = acc/denom;
  float m = act ? logit : -INFINITY;
  for (int off=32; off; off>>=1) m = fmaxf(m, __shfl_xor(m, off));
  float ex = act ? expf(logit - m) : 0.f;
  float ssum = ex;
  for (int off=32; off; off>>=1) ssum += __shfl_xor(ssum, off);
  if (act) out[(size_t)node*40 + lane] = logit - m - logf(ssum);
}

extern "C" void kernel_launch(void* const* d_in, const int* in_sizes, int n_in,
                              void* d_out, int out_size, void* d_ws, size_t ws_size,
                              hipStream_t stream){
  const float* inputs = (const float*)d_in[0];
  const float* W0  = (const float*)d_in[1];
  const float* al0 = (const float*)d_in[2];
  const float* ar0 = (const float*)d_in[3];
  const float* W1  = (const float*)d_in[4];
  const float* al1 = (const float*)d_in[5];
  const float* ar1 = (const float*)d_in[6];
  const float* W2  = (const float*)d_in[7];
  const float* al2 = (const float*)d_in[8];
  const float* ar2 = (const float*)d_in[9];
  const int* src = (const int*)d_in[10];
  const int* dst = (const int*)d_in[11];
  int N = in_sizes[0]/128;
  int E = in_sizes[10];
  int NB = (N + (1<<BKT_SHIFT) - 1) >> BKT_SHIFT;

  char* p = (char*)d_ws;
  auto carve = [&](size_t bytes)->char*{ char* q=p; p += ((bytes+255)/256)*256; return q; };
  unsigned short* Fb   = (unsigned short*)carve((size_t)N*128*2);
  unsigned short* Fb40 = (unsigned short*)carve((size_t)N*40*2);
  float* bufH = (float*)carve((size_t)N*128*4);     // fp32 hidden; pairs alias this during CSR build
  float* el  = (float*)carve((size_t)N*4*4);
  float* er  = (float*)carve((size_t)N*4*4);
  float* el2 = (float*)carve((size_t)N*4);
  float* er2 = (float*)carve((size_t)N*4);
  int* bkt_cursor  = (int*)carve((size_t)NB*4);     // zero-init
  int* bucket_base = (int*)carve((size_t)NB*4);
  int* row_ptr = (int*)carve((size_t)(N+1)*4);
  int* csr_src = (int*)carve((size_t)E*4);

  uint32* pairs = (uint32*)bufH;                    // NB*BKTCAP*4 = 9.6 MB < 51.2 MB

  hipMemsetAsync(bkt_cursor, 0, (size_t)NB*4, stream);
  int nPB = (E + PCHUNK - 1) / PCHUNK;
  k_partition<<<nPB, 256, 0, stream>>>(src, dst, bkt_cursor, pairs, E);
  k_scanbkt  <<<1, 512, 0, stream>>>(bkt_cursor, NB, bucket_base, row_ptr, N);
  k_build    <<<NB, 1024, 0, stream>>>(bkt_cursor, bucket_base, pairs, row_ptr, csr_src, N);

  int gRows = (N+63)/64;
  int gWave = (N+3)/4;
  int gRows42 = (N+127)/128;
  // layer 0
  k_gemm128<<<gRows,256,0,stream>>>(inputs, W0, al0, ar0, Fb, el, er, N);
  k_agg128 <<<gWave,256,0,stream>>>((const uint32*)Fb, el, er, row_ptr, csr_src, bufH, N);
  // layer 1
  k_gemm128<<<gRows,256,0,stream>>>(bufH, W1, al1, ar1, Fb, el, er, N);
  k_agg128 <<<gWave,256,0,stream>>>((const uint32*)Fb, el, er, row_ptr, csr_src, bufH, N);
  // layer 2
  k_gemm42 <<<gRows42,256,0,stream>>>(bufH, W2, al2, ar2, Fb40, el2, er2, N);
  k_agg40  <<<gWave,256,0,stream>>>(Fb40, el2, er2, row_ptr, csr_src, (float*)d_out, N);
}

// Round 6
// 409.177 us; speedup vs baseline: 2.5735x; 1.0078x over previous
//
#include <hip/hip_runtime.h>
#include <math.h>

typedef unsigned int uint32;

__device__ inline uint32 bf16rn(float x){
  uint32 b = __float_as_uint(x);
  return (b + 0x7fffu + ((b>>16)&1u)) >> 16;
}
__device__ inline float bf16lo(uint32 v){ return __uint_as_float(v<<16); }
__device__ inline float bf16hi(uint32 v){ return __uint_as_float(v & 0xffff0000u); }

#define BKT_SHIFT 9            // 512 nodes per bucket
#define BKTCAP 12288           // per-bucket record capacity
#define PCHUNK 8192            // edges per partition block

// ---------------- pass 1: LDS-staged bucket partition ----------------
__global__ __launch_bounds__(256) void k_partition(const int* __restrict__ src, const int* __restrict__ dst,
                        int* __restrict__ bkt_cursor, uint32* __restrict__ pairs, int E){
  __shared__ int cnt[512];
  __shared__ int base[512];
  int t = threadIdx.x;
  int blockBase = blockIdx.x * PCHUNK;
  for (int i=t; i<512; i+=256) cnt[i]=0;
  __syncthreads();
  #pragma unroll
  for (int i=0; i<PCHUNK/1024; i++){
    int e0 = blockBase + (i*256 + t)*4;
    if (e0+3 < E){
      int4 d4 = *(const int4*)&dst[e0];
      atomicAdd(&cnt[d4.x>>BKT_SHIFT],1);
      atomicAdd(&cnt[d4.y>>BKT_SHIFT],1);
      atomicAdd(&cnt[d4.z>>BKT_SHIFT],1);
      atomicAdd(&cnt[d4.w>>BKT_SHIFT],1);
    } else {
      for (int e=e0; e<E && e<e0+4; e++) atomicAdd(&cnt[dst[e]>>BKT_SHIFT],1);
    }
  }
  __syncthreads();
  for (int i=t; i<512; i+=256){
    int c = cnt[i];
    base[i] = c ? atomicAdd(&bkt_cursor[i], c) : 0;
    cnt[i] = 0;
  }
  __syncthreads();
  #pragma unroll
  for (int i=0; i<PCHUNK/1024; i++){
    int e0 = blockBase + (i*256 + t)*4;
    if (e0+3 < E){
      int4 s4 = *(const int4*)&src[e0];
      int4 d4 = *(const int4*)&dst[e0];
      int bx, pos;
      bx=d4.x>>BKT_SHIFT; pos=base[bx]+atomicAdd(&cnt[bx],1); if(pos<BKTCAP) pairs[(size_t)bx*BKTCAP+pos]=(uint32)s4.x|((uint32)(d4.x&511)<<22);
      bx=d4.y>>BKT_SHIFT; pos=base[bx]+atomicAdd(&cnt[bx],1); if(pos<BKTCAP) pairs[(size_t)bx*BKTCAP+pos]=(uint32)s4.y|((uint32)(d4.y&511)<<22);
      bx=d4.z>>BKT_SHIFT; pos=base[bx]+atomicAdd(&cnt[bx],1); if(pos<BKTCAP) pairs[(size_t)bx*BKTCAP+pos]=(uint32)s4.z|((uint32)(d4.z&511)<<22);
      bx=d4.w>>BKT_SHIFT; pos=base[bx]+atomicAdd(&cnt[bx],1); if(pos<BKTCAP) pairs[(size_t)bx*BKTCAP+pos]=(uint32)s4.w|((uint32)(d4.w&511)<<22);
    } else {
      for (int e=e0; e<E && e<e0+4; e++){
        int s=src[e], d=dst[e];
        int bx=d>>BKT_SHIFT; int pos=base[bx]+atomicAdd(&cnt[bx],1);
        if(pos<BKTCAP) pairs[(size_t)bx*BKTCAP+pos]=(uint32)s|((uint32)(d&511)<<22);
      }
    }
  }
}

// ---------------- pass 2: scan bucket totals ----------------
__global__ __launch_bounds__(512) void k_scanbkt(const int* __restrict__ bkt_cursor, int nb,
                      int* __restrict__ bucket_base, int* __restrict__ row_ptr, int N){
  __shared__ int sc[512];
  int t = threadIdx.x;
  int v = (t<nb) ? min(bkt_cursor[t], BKTCAP) : 0;
  sc[t]=v; __syncthreads();
  int x=v;
  for (int off=1; off<512; off<<=1){
    int y=(t>=off)? sc[t-off]:0;
    __syncthreads();
    x+=y; sc[t]=x;
    __syncthreads();
  }
  if (t<nb) bucket_base[t] = x - v;
  if (t==511) row_ptr[N] = x;
}

// ---------------- pass 3: per-bucket CSR build ----------------
__global__ __launch_bounds__(1024) void k_build(const int* __restrict__ bkt_cursor,
                        const int* __restrict__ bucket_base, const uint32* __restrict__ pairs,
                        int* __restrict__ row_ptr, int* __restrict__ csr_src, int N){
  __shared__ int hist[512];
  __shared__ int sc[512];
  __shared__ int cur[512];
  int b = blockIdx.x;
  int t = threadIdx.x;
  int cnt = bkt_cursor[b]; if (cnt > BKTCAP) cnt = BKTCAP;
  int base = bucket_base[b];
  const uint32* p = pairs + (size_t)b*BKTCAP;
  if (t<512) hist[t]=0;
  __syncthreads();
  for (int i=t; i<cnt; i+=1024) atomicAdd(&hist[p[i]>>22], 1);
  __syncthreads();
  int v = (t<512)? hist[t] : 0;
  if (t<512) sc[t]=v;
  __syncthreads();
  int x=v;
  for (int off=1; off<512; off<<=1){
    int y = (t<512 && t>=off)? sc[t-off] : 0;
    __syncthreads();
    if (t<512){ x+=y; sc[t]=x; }
    __syncthreads();
  }
  if (t<512){
    int excl = x - v;
    int gnode = (b<<BKT_SHIFT) + t;
    if (gnode < N) row_ptr[gnode] = base + excl;
    cur[t] = excl;
  }
  __syncthreads();
  for (int i=t; i<cnt; i+=1024){
    uint32 e = p[i];
    int pos = atomicAdd(&cur[e>>22], 1);
    csr_src[base + pos] = (int)(e & 0x3FFFFFu);
  }
}

// ---------------- GEMM [N,128]x[128,128] -> bf16 F + fused el/er ----------------
__global__ __launch_bounds__(256) void k_gemm128(const float* __restrict__ A, const float* __restrict__ W,
                                                 const float* __restrict__ al, const float* __restrict__ ar,
                                                 unsigned short* __restrict__ Fb,
                                                 float* __restrict__ el, float* __restrict__ er, int N){
  __shared__ float hs[32][68];
  __shared__ float ws[32][128];
  int t = threadIdx.x;
  int rowBase = blockIdx.x*64;
  int rg8 = (t>>5)*8;
  int cq  = (t&31)*4;
  float acc[8][4] = {};
  for (int kc=0; kc<128; kc+=32){
    {
      int row = t>>2; int kk = (t&3)*8;
      int grow = rowBase+row;
      float4 v0, v1;
      if (grow < N){
        v0 = *(const float4*)&A[(size_t)grow*128 + kc + kk];
        v1 = *(const float4*)&A[(size_t)grow*128 + kc + kk + 4];
      } else { v0 = make_float4(0,0,0,0); v1 = v0; }
      hs[kk+0][row]=v0.x; hs[kk+1][row]=v0.y; hs[kk+2][row]=v0.z; hs[kk+3][row]=v0.w;
      hs[kk+4][row]=v1.x; hs[kk+5][row]=v1.y; hs[kk+6][row]=v1.z; hs[kk+7][row]=v1.w;
    }
    {
      int k = t>>3; int c0 = (t&7)*16;
      const float4* wp = (const float4*)&W[(size_t)(kc+k)*128 + c0];
      float4 w0=wp[0], w1=wp[1], w2=wp[2], w3=wp[3];
      *(float4*)&ws[k][c0+ 0]=w0; *(float4*)&ws[k][c0+ 4]=w1;
      *(float4*)&ws[k][c0+ 8]=w2; *(float4*)&ws[k][c0+12]=w3;
    }
    __syncthreads();
    #pragma unroll
    for (int k=0;k<32;k++){
      float4 bv  = *(const float4*)&ws[k][cq];
      float4 av0 = *(const float4*)&hs[k][rg8];
      float4 av1 = *(const float4*)&hs[k][rg8+4];
      float a8[8] = {av0.x,av0.y,av0.z,av0.w,av1.x,av1.y,av1.z,av1.w};
      float b4[4] = {bv.x,bv.y,bv.z,bv.w};
      #pragma unroll
      for (int r=0;r<8;r++)
        #pragma unroll
        for (int c=0;c<4;c++)
          acc[r][c] = fmaf(a8[r], b4[c], acc[r][c]);
    }
    __syncthreads();
  }
  float al4[4], ar4[4];
  #pragma unroll
  for (int i=0;i<4;i++){ al4[i]=al[cq+i]; ar4[i]=ar[cq+i]; }
  int c = t&31;
  int h = c>>3;
  int rowTop = rowBase + rg8;
  #pragma unroll
  for (int r=0;r<8;r++){
    int row = rowTop + r;
    if (row < N){
      uint32 u0 = bf16rn(acc[r][0]) | (bf16rn(acc[r][1])<<16);
      uint32 u1 = bf16rn(acc[r][2]) | (bf16rn(acc[r][3])<<16);
      *(uint2*)(Fb + (size_t)row*128 + cq) = make_uint2(u0,u1);
    }
    float pl = acc[r][0]*al4[0]+acc[r][1]*al4[1]+acc[r][2]*al4[2]+acc[r][3]*al4[3];
    float pr = acc[r][0]*ar4[0]+acc[r][1]*ar4[1]+acc[r][2]*ar4[2]+acc[r][3]*ar4[3];
    pl += __shfl_xor(pl,1); pr += __shfl_xor(pr,1);
    pl += __shfl_xor(pl,2); pr += __shfl_xor(pr,2);
    pl += __shfl_xor(pl,4); pr += __shfl_xor(pr,4);
    if ((c&7)==0 && row < N){ el[(size_t)row*4+h]=pl; er[(size_t)row*4+h]=pr; }
  }
}

// ---------------- fused edge-softmax + aggregation (H=4,D=32) ----------------
// weight phase: one exp per (edge,head) across lanes; agg phase: scalar edge
// stream (s_load) + LDS weight broadcast; 2 fma + 2 unpack VALU per edge.
__global__ __launch_bounds__(256) void k_agg128(const uint32* __restrict__ Fu, const float* __restrict__ el,
                         const float* __restrict__ er, const int* __restrict__ row_ptr,
                         const int* __restrict__ csr_src, float* __restrict__ out, int N){
  __shared__ float wlds[4][272];
  int t = threadIdx.x;
  int lane = t & 63;
  int wv = t >> 6;
  int node = (blockIdx.x*blockDim.x + t)>>6;
  if (__builtin_amdgcn_readfirstlane(node) >= N) return;
  int h = lane>>4;
  int i0 = lane & 15;
  float erv = er[(size_t)node*4+h];
  int beg = row_ptr[node], end = row_ptr[node+1];
  int ubeg = __builtin_amdgcn_readfirstlane(beg);
  int uend = __builtin_amdgcn_readfirstlane(end);
  int udeg = uend - ubeg;
  int sv = (lane < udeg) ? csr_src[ubeg+lane] : 0;
  // ---- weight phase: 4 groups of 16 edges, lane owns (edge i0+16j, head h)
  float w4[4];
  #pragma unroll
  for (int j=0;j<4;j++){
    int eidx = i0 + 16*j;
    int sn = __shfl(sv, eidx);
    float x = 0.f;
    if (eidx < udeg){
      float ev = el[(size_t)sn*4+h] + erv;
      ev = ev>0.f ? ev : 0.2f*ev;
      x = __expf(ev);
    }
    w4[j] = x;
  }
  float dsum = (w4[0]+w4[1]) + (w4[2]+w4[3]);
  dsum += __shfl_xor(dsum, 1);
  dsum += __shfl_xor(dsum, 2);
  dsum += __shfl_xor(dsum, 4);
  dsum += __shfl_xor(dsum, 8);
  int wb = h*68 + i0;
  wlds[wv][wb   ] = w4[0];
  wlds[wv][wb+16] = w4[1];
  wlds[wv][wb+32] = w4[2];
  wlds[wv][wb+48] = w4[3];
  // ---- aggregation: scalar edge id + LDS weight + bf16 feat gather
  const int* sp = csr_src + ubeg;
  const float* wp = &wlds[wv][h*68];
  float acc0=0.f, acc1=0.f;
  int nm = udeg > 64 ? 64 : udeg;
  int i=0;
  for (; i+8<=nm; i+=8){
    #pragma unroll
    for (int k=0;k<8;k++){
      int s = sp[i+k];
      float wi = wp[i+k];
      uint32 v = Fu[(size_t)s*64 + lane];
      acc0 = fmaf(wi, bf16lo(v), acc0);
      acc1 = fmaf(wi, bf16hi(v), acc1);
    }
  }
  for (; i<nm; i++){
    int s = sp[i];
    float wi = wp[i];
    uint32 v = Fu[(size_t)s*64 + lane];
    acc0 = fmaf(wi, bf16lo(v), acc0);
    acc1 = fmaf(wi, bf16hi(v), acc1);
  }
  if (udeg > 64){
    for (int e=64; e<udeg; e++){
      int s = sp[e];
      float x = el[(size_t)s*4+h] + erv;
      x = x>0.f?x:0.2f*x; x=__expf(x);
      uint32 v = Fu[(size_t)s*64+lane];
      dsum += x;
      acc0 = fmaf(x, bf16lo(v), acc0);
      acc1 = fmaf(x, bf16hi(v), acc1);
    }
  }
  float inv = 1.0f/dsum;
  float o0 = acc0*inv, o1 = acc1*inv;
  o0 = o0>0.f ? o0 : expm1f(o0);
  o1 = o1>0.f ? o1 : expm1f(o1);
  *(float2*)&out[(size_t)node*128 + lane*2] = make_float2(o0,o1);
}

// ---------------- layer-2: tiled GEMM [N,128]x[128,40+2] -> bf16 Fb40, el2, er2 ----------------
__global__ __launch_bounds__(256) void k_gemm42(const float* __restrict__ A, const float* __restrict__ W,
                        const float* __restrict__ al, const float* __restrict__ ar,
                        unsigned short* __restrict__ Fb, float* __restrict__ el, float* __restrict__ er, int N){
  __shared__ float wfull[128*48];   // [k][48]: cols 0..39=W2, 40=wl, 41=wr, 42..47=0
  __shared__ float hs[32][132];     // transposed A chunk
  int t = threadIdx.x;
  int rowBase = blockIdx.x*128;
  for (int i=t; i<1280; i+=256){
    float4 v = *(const float4*)&W[i*4];
    int g = i*4;
    *(float4*)&wfull[(g/40)*48 + (g%40)] = v;
  }
  {
    int k = t & 127;
    const float* wrow = W + k*40;
    const float* a = (t < 128) ? al : ar;
    float s = 0.f;
    #pragma unroll
    for (int c=0;c<40;c++) s += wrow[c]*a[c];
    if (t < 128){
      wfull[k*48+40] = s;
      wfull[k*48+42] = 0.f; wfull[k*48+43] = 0.f; wfull[k*48+44] = 0.f;
    } else {
      wfull[k*48+41] = s;
      wfull[k*48+45] = 0.f; wfull[k*48+46] = 0.f; wfull[k*48+47] = 0.f;
    }
  }
  int c0 = (t&7)*6;
  int r0 = (t>>3)*4;
  float acc[4][6] = {};
  for (int kc=0; kc<128; kc+=32){
    {
      int row = t>>1; int kk0 = (t&1)*16;
      int grow = rowBase + row;
      #pragma unroll
      for (int j=0;j<4;j++){
        float4 v = (grow<N) ? *(const float4*)&A[(size_t)grow*128 + kc + kk0 + 4*j] : make_float4(0,0,0,0);
        hs[kk0+4*j+0][row]=v.x; hs[kk0+4*j+1][row]=v.y; hs[kk0+4*j+2][row]=v.z; hs[kk0+4*j+3][row]=v.w;
      }
    }
    __syncthreads();
    #pragma unroll
    for (int k=0;k<32;k++){
      float4 av = *(const float4*)&hs[k][r0];
      const float* wp = &wfull[(kc+k)*48 + c0];
      float2 b01 = *(const float2*)&wp[0];
      float2 b23 = *(const float2*)&wp[2];
      float2 b45 = *(const float2*)&wp[4];
      float a4[4] = {av.x,av.y,av.z,av.w};
      float b6[6] = {b01.x,b01.y,b23.x,b23.y,b45.x,b45.y};
      #pragma unroll
      for (int r=0;r<4;r++)
        #pragma unroll
        for (int c=0;c<6;c++)
          acc[r][c] = fmaf(a4[r], b6[c], acc[r][c]);
    }
    __syncthreads();
  }
  #pragma unroll
  for (int r=0;r<4;r++){
    int row = rowBase + r0 + r;
    if (row >= N) break;
    if (c0 < 40){
      #pragma unroll
      for (int j=0;j<6;j+=2){
        int col = c0 + j;
        if (col < 40){
          uint32 u = bf16rn(acc[r][j]) | (bf16rn(acc[r][j+1])<<16);
          *(uint32*)(Fb + (size_t)row*40 + col) = u;
        }
      }
      if (c0 == 36){ el[row] = acc[r][4]; er[row] = acc[r][5]; }
    }
  }
}

// ---------------- final aggregation (H=1,D=40) + log_softmax ----------------
__global__ __launch_bounds__(256) void k_agg40(const unsigned short* __restrict__ Fb, const float* __restrict__ el,
                       const float* __restrict__ er, const int* __restrict__ row_ptr,
                       const int* __restrict__ csr_src, float* __restrict__ out, int N){
  __shared__ float wlds[4][64];
  int t = threadIdx.x;
  int lane = t & 63;
  int wv = t >> 6;
  int node = (blockIdx.x*blockDim.x + t)>>6;
  if (__builtin_amdgcn_readfirstlane(node) >= N) return;
  bool act = lane<40;
  int l40 = act ? lane : 0;
  float erv = er[node];
  int beg = row_ptr[node], end = row_ptr[node+1];
  int ubeg = __builtin_amdgcn_readfirstlane(beg);
  int uend = __builtin_amdgcn_readfirstlane(end);
  int udeg = uend - ubeg;
  int sv = (lane < udeg) ? csr_src[ubeg+lane] : 0;
  // weight phase: one edge per lane
  float w = 0.f;
  if (lane < udeg){
    float ev = el[sv] + erv;
    ev = ev>0.f ? ev : 0.2f*ev;
    w = __expf(ev);
  }
  float dsum = w;
  dsum += __shfl_xor(dsum, 1);
  dsum += __shfl_xor(dsum, 2);
  dsum += __shfl_xor(dsum, 4);
  dsum += __shfl_xor(dsum, 8);
  dsum += __shfl_xor(dsum, 16);
  dsum += __shfl_xor(dsum, 32);
  wlds[wv][lane] = w;
  // aggregation
  const int* sp = csr_src + ubeg;
  float acc=0.f;
  int nm = udeg > 64 ? 64 : udeg;
  int i=0;
  for (; i+8<=nm; i+=8){
    #pragma unroll
    for (int k=0;k<8;k++){
      int s = sp[i+k];
      float wi = wlds[wv][i+k];
      unsigned short f = Fb[(size_t)s*40 + l40];
      acc = fmaf(wi, __uint_as_float(((uint32)f)<<16), acc);
    }
  }
  for (; i<nm; i++){
    int s = sp[i];
    float wi = wlds[wv][i];
    unsigned short f = Fb[(size_t)s*40 + l40];
    acc = fmaf(wi, __uint_as_float(((uint32)f)<<16), acc);
  }
  if (udeg > 64){
    for (int e=64; e<udeg; e++){
      int s = sp[e];
      float x = el[s] + erv;
      x = x>0.f?x:0.2f*x; x=__expf(x);
      unsigned short f = Fb[(size_t)s*40 + l40];
      dsum += x;
      acc = fmaf(x, __uint_as_float(((uint32)f)<<16), acc);
    }
  }
  float logit = acc/dsum;
  float m = act ? logit : -INFINITY;
  for (int off=32; off; off>>=1) m = fmaxf(m, __shfl_xor(m, off));
  float ex = act ? expf(logit - m) : 0.f;
  float ssum = ex;
  for (int off=32; off; off>>=1) ssum += __shfl_xor(ssum, off);
  if (act) out[(size_t)node*40 + lane] = logit - m - logf(ssum);
}

extern "C" void kernel_launch(void* const* d_in, const int* in_sizes, int n_in,
                              void* d_out, int out_size, void* d_ws, size_t ws_size,
                              hipStream_t stream){
  const float* inputs = (const float*)d_in[0];
  const float* W0  = (const float*)d_in[1];
  const float* al0 = (const float*)d_in[2];
  const float* ar0 = (const float*)d_in[3];
  const float* W1  = (const float*)d_in[4];
  const float* al1 = (const float*)d_in[5];
  const float* ar1 = (const float*)d_in[6];
  const float* W2  = (const float*)d_in[7];
  const float* al2 = (const float*)d_in[8];
  const float* ar2 = (const float*)d_in[9];
  const int* src = (const int*)d_in[10];
  const int* dst = (const int*)d_in[11];
  int N = in_sizes[0]/128;
  int E = in_sizes[10];
  int NB = (N + (1<<BKT_SHIFT) - 1) >> BKT_SHIFT;

  char* p = (char*)d_ws;
  auto carve = [&](size_t bytes)->char*{ char* q=p; p += ((bytes+255)/256)*256; return q; };
  unsigned short* Fb   = (unsigned short*)carve((size_t)N*128*2);
  unsigned short* Fb40 = (unsigned short*)carve((size_t)N*40*2);
  float* bufH = (float*)carve((size_t)N*128*4);     // fp32 hidden; pairs alias this during CSR build
  float* el  = (float*)carve((size_t)N*4*4);
  float* er  = (float*)carve((size_t)N*4*4);
  float* el2 = (float*)carve((size_t)N*4);
  float* er2 = (float*)carve((size_t)N*4);
  int* bkt_cursor  = (int*)carve((size_t)NB*4);     // zero-init
  int* bucket_base = (int*)carve((size_t)NB*4);
  int* row_ptr = (int*)carve((size_t)(N+1)*4);
  int* csr_src = (int*)carve((size_t)E*4);

  uint32* pairs = (uint32*)bufH;                    // NB*BKTCAP*4 = 9.6 MB < 51.2 MB

  hipMemsetAsync(bkt_cursor, 0, (size_t)NB*4, stream);
  int nPB = (E + PCHUNK - 1) / PCHUNK;
  k_partition<<<nPB, 256, 0, stream>>>(src, dst, bkt_cursor, pairs, E);
  k_scanbkt  <<<1, 512, 0, stream>>>(bkt_cursor, NB, bucket_base, row_ptr, N);
  k_build    <<<NB, 1024, 0, stream>>>(bkt_cursor, bucket_base, pairs, row_ptr, csr_src, N);

  int gRows = (N+63)/64;
  int gWave = (N+3)/4;
  int gRows42 = (N+127)/128;
  // layer 0
  k_gemm128<<<gRows,256,0,stream>>>(inputs, W0, al0, ar0, Fb, el, er, N);
  k_agg128 <<<gWave,256,0,stream>>>((const uint32*)Fb, el, er, row_ptr, csr_src, bufH, N);
  // layer 1
  k_gemm128<<<gRows,256,0,stream>>>(bufH, W1, al1, ar1, Fb, el, er, N);
  k_agg128 <<<gWave,256,0,stream>>>((const uint32*)Fb, el, er, row_ptr, csr_src, bufH, N);
  // layer 2
  k_gemm42 <<<gRows42,256,0,stream>>>(bufH, W2, al2, ar2, Fb40, el2, er2, N);
  k_agg40  <<<gWave,256,0,stream>>>(Fb40, el2, er2, row_ptr, csr_src, (float*)d_out, N);
}

// Round 7
// 406.868 us; speedup vs baseline: 2.5881x; 1.0057x over previous
//
#include <hip/hip_runtime.h>
#include <math.h>

typedef unsigned int uint32;
typedef unsigned short ushort;

__device__ inline uint32 bf16rn(float x){
  uint32 b = __float_as_uint(x);
  return (b + 0x7fffu + ((b>>16)&1u)) >> 16;
}
__device__ inline float bf16lo(uint32 v){ return __uint_as_float(v<<16); }
__device__ inline float bf16hi(uint32 v){ return __uint_as_float(v & 0xffff0000u); }

#define BKT_SHIFT 9            // 512 nodes per bucket
#define BKTCAP 12288           // per-bucket record capacity
#define PCHUNK 8192            // edges per partition block

// ---------------- pass 1: LDS-staged bucket partition ----------------
__global__ __launch_bounds__(256) void k_partition(const int* __restrict__ src, const int* __restrict__ dst,
                        int* __restrict__ bkt_cursor, uint32* __restrict__ pairs, int E){
  __shared__ int cnt[512];
  __shared__ int base[512];
  int t = threadIdx.x;
  int blockBase = blockIdx.x * PCHUNK;
  for (int i=t; i<512; i+=256) cnt[i]=0;
  __syncthreads();
  #pragma unroll
  for (int i=0; i<PCHUNK/1024; i++){
    int e0 = blockBase + (i*256 + t)*4;
    if (e0+3 < E){
      int4 d4 = *(const int4*)&dst[e0];
      atomicAdd(&cnt[d4.x>>BKT_SHIFT],1);
      atomicAdd(&cnt[d4.y>>BKT_SHIFT],1);
      atomicAdd(&cnt[d4.z>>BKT_SHIFT],1);
      atomicAdd(&cnt[d4.w>>BKT_SHIFT],1);
    } else {
      for (int e=e0; e<E && e<e0+4; e++) atomicAdd(&cnt[dst[e]>>BKT_SHIFT],1);
    }
  }
  __syncthreads();
  for (int i=t; i<512; i+=256){
    int c = cnt[i];
    base[i] = c ? atomicAdd(&bkt_cursor[i], c) : 0;
    cnt[i] = 0;
  }
  __syncthreads();
  #pragma unroll
  for (int i=0; i<PCHUNK/1024; i++){
    int e0 = blockBase + (i*256 + t)*4;
    if (e0+3 < E){
      int4 s4 = *(const int4*)&src[e0];
      int4 d4 = *(const int4*)&dst[e0];
      int bx, pos;
      bx=d4.x>>BKT_SHIFT; pos=base[bx]+atomicAdd(&cnt[bx],1); if(pos<BKTCAP) pairs[(size_t)bx*BKTCAP+pos]=(uint32)s4.x|((uint32)(d4.x&511)<<22);
      bx=d4.y>>BKT_SHIFT; pos=base[bx]+atomicAdd(&cnt[bx],1); if(pos<BKTCAP) pairs[(size_t)bx*BKTCAP+pos]=(uint32)s4.y|((uint32)(d4.y&511)<<22);
      bx=d4.z>>BKT_SHIFT; pos=base[bx]+atomicAdd(&cnt[bx],1); if(pos<BKTCAP) pairs[(size_t)bx*BKTCAP+pos]=(uint32)s4.z|((uint32)(d4.z&511)<<22);
      bx=d4.w>>BKT_SHIFT; pos=base[bx]+atomicAdd(&cnt[bx],1); if(pos<BKTCAP) pairs[(size_t)bx*BKTCAP+pos]=(uint32)s4.w|((uint32)(d4.w&511)<<22);
    } else {
      for (int e=e0; e<E && e<e0+4; e++){
        int s=src[e], d=dst[e];
        int bx=d>>BKT_SHIFT; int pos=base[bx]+atomicAdd(&cnt[bx],1);
        if(pos<BKTCAP) pairs[(size_t)bx*BKTCAP+pos]=(uint32)s|((uint32)(d&511)<<22);
      }
    }
  }
}

// ---------------- pass 2: scan bucket totals ----------------
__global__ __launch_bounds__(512) void k_scanbkt(const int* __restrict__ bkt_cursor, int nb,
                      int* __restrict__ bucket_base, int* __restrict__ row_ptr, int N){
  __shared__ int sc[512];
  int t = threadIdx.x;
  int v = (t<nb) ? min(bkt_cursor[t], BKTCAP) : 0;
  sc[t]=v; __syncthreads();
  int x=v;
  for (int off=1; off<512; off<<=1){
    int y=(t>=off)? sc[t-off]:0;
    __syncthreads();
    x+=y; sc[t]=x;
    __syncthreads();
  }
  if (t<nb) bucket_base[t] = x - v;
  if (t==511) row_ptr[N] = x;
}

// ---------------- pass 3: per-bucket CSR build ----------------
__global__ __launch_bounds__(1024) void k_build(const int* __restrict__ bkt_cursor,
                        const int* __restrict__ bucket_base, const uint32* __restrict__ pairs,
                        int* __restrict__ row_ptr, int* __restrict__ csr_src, int N){
  __shared__ int hist[512];
  __shared__ int sc[512];
  __shared__ int cur[512];
  int b = blockIdx.x;
  int t = threadIdx.x;
  int cnt = bkt_cursor[b]; if (cnt > BKTCAP) cnt = BKTCAP;
  int base = bucket_base[b];
  const uint32* p = pairs + (size_t)b*BKTCAP;
  if (t<512) hist[t]=0;
  __syncthreads();
  for (int i=t; i<cnt; i+=1024) atomicAdd(&hist[p[i]>>22], 1);
  __syncthreads();
  int v = (t<512)? hist[t] : 0;
  if (t<512) sc[t]=v;
  __syncthreads();
  int x=v;
  for (int off=1; off<512; off<<=1){
    int y = (t<512 && t>=off)? sc[t-off] : 0;
    __syncthreads();
    if (t<512){ x+=y; sc[t]=x; }
    __syncthreads();
  }
  if (t<512){
    int excl = x - v;
    int gnode = (b<<BKT_SHIFT) + t;
    if (gnode < N) row_ptr[gnode] = base + excl;
    cur[t] = excl;
  }
  __syncthreads();
  for (int i=t; i<cnt; i+=1024){
    uint32 e = p[i];
    int pos = atomicAdd(&cur[e>>22], 1);
    csr_src[base + pos] = (int)(e & 0x3FFFFFu);
  }
}

// ---------------- GEMM [N,128]x[128,128] -> bf16 F + fused el/er ----------------
// BF16A=false: A fp32 (layer 0 inputs). BF16A=true: A bf16 (hidden state).
template<bool BF16A>
__global__ __launch_bounds__(256) void k_gemm128T(const void* __restrict__ Av, const float* __restrict__ W,
                                                 const float* __restrict__ al, const float* __restrict__ ar,
                                                 ushort* __restrict__ Fb,
                                                 float* __restrict__ el, float* __restrict__ er, int N){
  __shared__ float hs[32][68];
  __shared__ float ws[32][128];
  int t = threadIdx.x;
  int rowBase = blockIdx.x*64;
  int rg8 = (t>>5)*8;
  int cq  = (t&31)*4;
  float acc[8][4] = {};
  for (int kc=0; kc<128; kc+=32){
    {
      int row = t>>2; int kk = (t&3)*8;
      int grow = rowBase+row;
      float a8[8];
      if (grow < N){
        if constexpr (BF16A){
          const ushort* Ab = (const ushort*)Av;
          uint4 u = *(const uint4*)&Ab[(size_t)grow*128 + kc + kk];
          a8[0]=bf16lo(u.x); a8[1]=bf16hi(u.x); a8[2]=bf16lo(u.y); a8[3]=bf16hi(u.y);
          a8[4]=bf16lo(u.z); a8[5]=bf16hi(u.z); a8[6]=bf16lo(u.w); a8[7]=bf16hi(u.w);
        } else {
          const float* Af = (const float*)Av;
          float4 v0 = *(const float4*)&Af[(size_t)grow*128 + kc + kk];
          float4 v1 = *(const float4*)&Af[(size_t)grow*128 + kc + kk + 4];
          a8[0]=v0.x; a8[1]=v0.y; a8[2]=v0.z; a8[3]=v0.w;
          a8[4]=v1.x; a8[5]=v1.y; a8[6]=v1.z; a8[7]=v1.w;
        }
      } else {
        #pragma unroll
        for (int j=0;j<8;j++) a8[j]=0.f;
      }
      #pragma unroll
      for (int j=0;j<8;j++) hs[kk+j][row]=a8[j];
    }
    {
      int k = t>>3; int c0 = (t&7)*16;
      const float4* wp = (const float4*)&W[(size_t)(kc+k)*128 + c0];
      float4 w0=wp[0], w1=wp[1], w2=wp[2], w3=wp[3];
      *(float4*)&ws[k][c0+ 0]=w0; *(float4*)&ws[k][c0+ 4]=w1;
      *(float4*)&ws[k][c0+ 8]=w2; *(float4*)&ws[k][c0+12]=w3;
    }
    __syncthreads();
    #pragma unroll
    for (int k=0;k<32;k++){
      float4 bv  = *(const float4*)&ws[k][cq];
      float4 av0 = *(const float4*)&hs[k][rg8];
      float4 av1 = *(const float4*)&hs[k][rg8+4];
      float a8[8] = {av0.x,av0.y,av0.z,av0.w,av1.x,av1.y,av1.z,av1.w};
      float b4[4] = {bv.x,bv.y,bv.z,bv.w};
      #pragma unroll
      for (int r=0;r<8;r++)
        #pragma unroll
        for (int c=0;c<4;c++)
          acc[r][c] = fmaf(a8[r], b4[c], acc[r][c]);
    }
    __syncthreads();
  }
  float al4[4], ar4[4];
  #pragma unroll
  for (int i=0;i<4;i++){ al4[i]=al[cq+i]; ar4[i]=ar[cq+i]; }
  int c = t&31;
  int h = c>>3;
  int rowTop = rowBase + rg8;
  #pragma unroll
  for (int r=0;r<8;r++){
    int row = rowTop + r;
    if (row < N){
      uint32 u0 = bf16rn(acc[r][0]) | (bf16rn(acc[r][1])<<16);
      uint32 u1 = bf16rn(acc[r][2]) | (bf16rn(acc[r][3])<<16);
      *(uint2*)(Fb + (size_t)row*128 + cq) = make_uint2(u0,u1);
    }
    float pl = acc[r][0]*al4[0]+acc[r][1]*al4[1]+acc[r][2]*al4[2]+acc[r][3]*al4[3];
    float pr = acc[r][0]*ar4[0]+acc[r][1]*ar4[1]+acc[r][2]*ar4[2]+acc[r][3]*ar4[3];
    pl += __shfl_xor(pl,1); pr += __shfl_xor(pr,1);
    pl += __shfl_xor(pl,2); pr += __shfl_xor(pr,2);
    pl += __shfl_xor(pl,4); pr += __shfl_xor(pr,4);
    if ((c&7)==0 && row < N){ el[(size_t)row*4+h]=pl; er[(size_t)row*4+h]=pr; }
  }
}

// ---------------- fused edge-softmax + aggregation (H=4,D=32) ----------------
// weight phase: one exp per (edge,head); agg: scalar edge stream + double-buffered
// bf16 feat gather (8 loads in flight across iterations); bf16 ELU output.
__global__ __launch_bounds__(256) void k_agg128(const uint32* __restrict__ Fu, const float* __restrict__ el,
                         const float* __restrict__ er, const int* __restrict__ row_ptr,
                         const int* __restrict__ csr_src, ushort* __restrict__ out, int N){
  __shared__ float wlds[4][272];
  int t = threadIdx.x;
  int lane = t & 63;
  int wv = t >> 6;
  int node = (blockIdx.x*blockDim.x + t)>>6;
  if (__builtin_amdgcn_readfirstlane(node) >= N) return;
  int h = lane>>4;
  int i0 = lane & 15;
  float erv = er[(size_t)node*4+h];
  int beg = row_ptr[node], end = row_ptr[node+1];
  int ubeg = __builtin_amdgcn_readfirstlane(beg);
  int uend = __builtin_amdgcn_readfirstlane(end);
  int udeg = uend - ubeg;
  int sv = (lane < udeg) ? csr_src[ubeg+lane] : 0;
  // ---- weight phase: issue all el gathers first, then exp
  int sn[4]; float evv[4];
  #pragma unroll
  for (int j=0;j<4;j++) sn[j] = __shfl(sv, i0 + 16*j);
  #pragma unroll
  for (int j=0;j<4;j++) evv[j] = el[(size_t)sn[j]*4+h];
  float w4[4];
  #pragma unroll
  for (int j=0;j<4;j++){
    float ev = evv[j] + erv;
    ev = ev>0.f ? ev : 0.2f*ev;
    w4[j] = (i0 + 16*j < udeg) ? __expf(ev) : 0.f;
  }
  float dsum = (w4[0]+w4[1]) + (w4[2]+w4[3]);
  dsum += __shfl_xor(dsum, 1);
  dsum += __shfl_xor(dsum, 2);
  dsum += __shfl_xor(dsum, 4);
  dsum += __shfl_xor(dsum, 8);
  int wb = h*68 + i0;
  wlds[wv][wb   ] = w4[0];
  wlds[wv][wb+16] = w4[1];
  wlds[wv][wb+32] = w4[2];
  wlds[wv][wb+48] = w4[3];
  // ---- aggregation: double-buffered gather
  const int* sp = csr_src + ubeg;
  const float* wp = &wlds[wv][h*68];
  float acc0=0.f, acc1=0.f;
  int nm = udeg > 64 ? 64 : udeg;
  uint32 vb[8];
  #pragma unroll
  for (int k=0;k<8;k++) vb[k] = (k<nm) ? Fu[(size_t)sp[k]*64 + lane] : 0u;
  int i=0;
  for (; i+16<=nm; i+=8){
    uint32 vn[8];
    #pragma unroll
    for (int k=0;k<8;k++) vn[k] = Fu[(size_t)sp[i+8+k]*64 + lane];
    #pragma unroll
    for (int k=0;k<8;k++){
      float wi = wp[i+k];
      acc0 = fmaf(wi, bf16lo(vb[k]), acc0);
      acc1 = fmaf(wi, bf16hi(vb[k]), acc1);
    }
    #pragma unroll
    for (int k=0;k<8;k++) vb[k]=vn[k];
  }
  {
    int lim = nm - i; if (lim > 8) lim = 8;
    #pragma unroll
    for (int k=0;k<8;k++) if (k<lim){
      float wi = wp[i+k];
      acc0 = fmaf(wi, bf16lo(vb[k]), acc0);
      acc1 = fmaf(wi, bf16hi(vb[k]), acc1);
    }
    for (int e=i+8; e<nm; e++){
      float wi = wp[e];
      uint32 v = Fu[(size_t)sp[e]*64 + lane];
      acc0 = fmaf(wi, bf16lo(v), acc0);
      acc1 = fmaf(wi, bf16hi(v), acc1);
    }
  }
  if (udeg > 64){
    for (int e=64; e<udeg; e++){
      int s = sp[e];
      float x = el[(size_t)s*4+h] + erv;
      x = x>0.f?x:0.2f*x; x=__expf(x);
      uint32 v = Fu[(size_t)s*64+lane];
      dsum += x;
      acc0 = fmaf(x, bf16lo(v), acc0);
      acc1 = fmaf(x, bf16hi(v), acc1);
    }
  }
  float inv = 1.0f/dsum;
  float o0 = acc0*inv, o1 = acc1*inv;
  o0 = o0>0.f ? o0 : expm1f(o0);
  o1 = o1>0.f ? o1 : expm1f(o1);
  uint32 uo = bf16rn(o0) | (bf16rn(o1)<<16);
  *(uint32*)(out + (size_t)node*128 + lane*2) = uo;
}

// ---------------- layer-2: tiled GEMM [N,128(bf16)]x[128,40+2] -> bf16 Fb40, el2, er2 ----------------
__global__ __launch_bounds__(256) void k_gemm42(const ushort* __restrict__ A, const float* __restrict__ W,
                        const float* __restrict__ al, const float* __restrict__ ar,
                        ushort* __restrict__ Fb, float* __restrict__ el, float* __restrict__ er, int N){
  __shared__ float wfull[128*48];   // [k][48]: cols 0..39=W2, 40=wl, 41=wr, 42..47=0
  __shared__ float hs[32][132];     // transposed A chunk
  int t = threadIdx.x;
  int rowBase = blockIdx.x*128;
  for (int i=t; i<1280; i+=256){
    float4 v = *(const float4*)&W[i*4];
    int g = i*4;
    *(float4*)&wfull[(g/40)*48 + (g%40)] = v;
  }
  {
    int k = t & 127;
    const float* wrow = W + k*40;
    const float* a = (t < 128) ? al : ar;
    float s = 0.f;
    #pragma unroll
    for (int c=0;c<40;c++) s += wrow[c]*a[c];
    if (t < 128){
      wfull[k*48+40] = s;
      wfull[k*48+42] = 0.f; wfull[k*48+43] = 0.f; wfull[k*48+44] = 0.f;
    } else {
      wfull[k*48+41] = s;
      wfull[k*48+45] = 0.f; wfull[k*48+46] = 0.f; wfull[k*48+47] = 0.f;
    }
  }
  int c0 = (t&7)*6;
  int r0 = (t>>3)*4;
  float acc[4][6] = {};
  for (int kc=0; kc<128; kc+=32){
    {
      int row = t>>1; int kk0 = (t&1)*16;
      int grow = rowBase + row;
      if (grow < N){
        uint4 u0 = *(const uint4*)&A[(size_t)grow*128 + kc + kk0];
        uint4 u1 = *(const uint4*)&A[(size_t)grow*128 + kc + kk0 + 8];
        hs[kk0+ 0][row]=bf16lo(u0.x); hs[kk0+ 1][row]=bf16hi(u0.x);
        hs[kk0+ 2][row]=bf16lo(u0.y); hs[kk0+ 3][row]=bf16hi(u0.y);
        hs[kk0+ 4][row]=bf16lo(u0.z); hs[kk0+ 5][row]=bf16hi(u0.z);
        hs[kk0+ 6][row]=bf16lo(u0.w); hs[kk0+ 7][row]=bf16hi(u0.w);
        hs[kk0+ 8][row]=bf16lo(u1.x); hs[kk0+ 9][row]=bf16hi(u1.x);
        hs[kk0+10][row]=bf16lo(u1.y); hs[kk0+11][row]=bf16hi(u1.y);
        hs[kk0+12][row]=bf16lo(u1.z); hs[kk0+13][row]=bf16hi(u1.z);
        hs[kk0+14][row]=bf16lo(u1.w); hs[kk0+15][row]=bf16hi(u1.w);
      } else {
        #pragma unroll
        for (int j=0;j<16;j++) hs[kk0+j][row]=0.f;
      }
    }
    __syncthreads();
    #pragma unroll
    for (int k=0;k<32;k++){
      float4 av = *(const float4*)&hs[k][r0];
      const float* wp = &wfull[(kc+k)*48 + c0];
      float2 b01 = *(const float2*)&wp[0];
      float2 b23 = *(const float2*)&wp[2];
      float2 b45 = *(const float2*)&wp[4];
      float a4[4] = {av.x,av.y,av.z,av.w};
      float b6[6] = {b01.x,b01.y,b23.x,b23.y,b45.x,b45.y};
      #pragma unroll
      for (int r=0;r<4;r++)
        #pragma unroll
        for (int c=0;c<6;c++)
          acc[r][c] = fmaf(a4[r], b6[c], acc[r][c]);
    }
    __syncthreads();
  }
  #pragma unroll
  for (int r=0;r<4;r++){
    int row = rowBase + r0 + r;
    if (row >= N) break;
    if (c0 < 40){
      #pragma unroll
      for (int j=0;j<6;j+=2){
        int col = c0 + j;
        if (col < 40){
          uint32 u = bf16rn(acc[r][j]) | (bf16rn(acc[r][j+1])<<16);
          *(uint32*)(Fb + (size_t)row*40 + col) = u;
        }
      }
      if (c0 == 36){ el[row] = acc[r][4]; er[row] = acc[r][5]; }
    }
  }
}

// ---------------- final aggregation (H=1,D=40) + log_softmax ----------------
__global__ __launch_bounds__(256) void k_agg40(const ushort* __restrict__ Fb, const float* __restrict__ el,
                       const float* __restrict__ er, const int* __restrict__ row_ptr,
                       const int* __restrict__ csr_src, float* __restrict__ out, int N){
  __shared__ float wlds[4][64];
  int t = threadIdx.x;
  int lane = t & 63;
  int wv = t >> 6;
  int node = (blockIdx.x*blockDim.x + t)>>6;
  if (__builtin_amdgcn_readfirstlane(node) >= N) return;
  bool act = lane<40;
  int l40 = act ? lane : 0;
  float erv = er[node];
  int beg = row_ptr[node], end = row_ptr[node+1];
  int ubeg = __builtin_amdgcn_readfirstlane(beg);
  int uend = __builtin_amdgcn_readfirstlane(end);
  int udeg = uend - ubeg;
  int sv = (lane < udeg) ? csr_src[ubeg+lane] : 0;
  float w = 0.f;
  if (lane < udeg){
    float ev = el[sv] + erv;
    ev = ev>0.f ? ev : 0.2f*ev;
    w = __expf(ev);
  }
  float dsum = w;
  dsum += __shfl_xor(dsum, 1);
  dsum += __shfl_xor(dsum, 2);
  dsum += __shfl_xor(dsum, 4);
  dsum += __shfl_xor(dsum, 8);
  dsum += __shfl_xor(dsum, 16);
  dsum += __shfl_xor(dsum, 32);
  wlds[wv][lane] = w;
  const int* sp = csr_src + ubeg;
  float acc=0.f;
  int nm = udeg > 64 ? 64 : udeg;
  ushort fb8[8];
  #pragma unroll
  for (int k=0;k<8;k++) fb8[k] = (k<nm) ? Fb[(size_t)sp[k]*40 + l40] : (ushort)0;
  int i=0;
  for (; i+16<=nm; i+=8){
    ushort fn[8];
    #pragma unroll
    for (int k=0;k<8;k++) fn[k] = Fb[(size_t)sp[i+8+k]*40 + l40];
    #pragma unroll
    for (int k=0;k<8;k++){
      float wi = wlds[wv][i+k];
      acc = fmaf(wi, __uint_as_float(((uint32)fb8[k])<<16), acc);
    }
    #pragma unroll
    for (int k=0;k<8;k++) fb8[k]=fn[k];
  }
  {
    int lim = nm - i; if (lim > 8) lim = 8;
    #pragma unroll
    for (int k=0;k<8;k++) if (k<lim){
      float wi = wlds[wv][i+k];
      acc = fmaf(wi, __uint_as_float(((uint32)fb8[k])<<16), acc);
    }
    for (int e=i+8; e<nm; e++){
      float wi = wlds[wv][e];
      ushort f = Fb[(size_t)sp[e]*40 + l40];
      acc = fmaf(wi, __uint_as_float(((uint32)f)<<16), acc);
    }
  }
  if (udeg > 64){
    for (int e=64; e<udeg; e++){
      int s = sp[e];
      float x = el[s] + erv;
      x = x>0.f?x:0.2f*x; x=__expf(x);
      ushort f = Fb[(size_t)s*40 + l40];
      dsum += x;
      acc = fmaf(x, __uint_as_float(((uint32)f)<<16), acc);
    }
  }
  float logit = acc/dsum;
  float m = act ? logit : -INFINITY;
  for (int off=32; off; off>>=1) m = fmaxf(m, __shfl_xor(m, off));
  float ex = act ? expf(logit - m) : 0.f;
  float ssum = ex;
  for (int off=32; off; off>>=1) ssum += __shfl_xor(ssum, off);
  if (act) out[(size_t)node*40 + lane] = logit - m - logf(ssum);
}

extern "C" void kernel_launch(void* const* d_in, const int* in_sizes, int n_in,
                              void* d_out, int out_size, void* d_ws, size_t ws_size,
                              hipStream_t stream){
  const float* inputs = (const float*)d_in[0];
  const float* W0  = (const float*)d_in[1];
  const float* al0 = (const float*)d_in[2];
  const float* ar0 = (const float*)d_in[3];
  const float* W1  = (const float*)d_in[4];
  const float* al1 = (const float*)d_in[5];
  const float* ar1 = (const float*)d_in[6];
  const float* W2  = (const float*)d_in[7];
  const float* al2 = (const float*)d_in[8];
  const float* ar2 = (const float*)d_in[9];
  const int* src = (const int*)d_in[10];
  const int* dst = (const int*)d_in[11];
  int N = in_sizes[0]/128;
  int E = in_sizes[10];
  int NB = (N + (1<<BKT_SHIFT) - 1) >> BKT_SHIFT;

  char* p = (char*)d_ws;
  auto carve = [&](size_t bytes)->char*{ char* q=p; p += ((bytes+255)/256)*256; return q; };
  ushort* Fb   = (ushort*)carve((size_t)N*128*2);   // bf16 feat
  ushort* Fb40 = (ushort*)carve((size_t)N*40*2);    // bf16 layer-2 feat
  ushort* bufH = (ushort*)carve((size_t)N*128*2);   // bf16 hidden; pairs alias this during CSR build
  float* el  = (float*)carve((size_t)N*4*4);
  float* er  = (float*)carve((size_t)N*4*4);
  float* el2 = (float*)carve((size_t)N*4);
  float* er2 = (float*)carve((size_t)N*4);
  int* bkt_cursor  = (int*)carve((size_t)NB*4);     // zero-init
  int* bucket_base = (int*)carve((size_t)NB*4);
  int* row_ptr = (int*)carve((size_t)(N+1)*4);
  int* csr_src = (int*)carve((size_t)E*4);

  uint32* pairs = (uint32*)bufH;                    // NB*BKTCAP*4 = 9.6 MB < 25.6 MB

  hipMemsetAsync(bkt_cursor, 0, (size_t)NB*4, stream);
  int nPB = (E + PCHUNK - 1) / PCHUNK;
  k_partition<<<nPB, 256, 0, stream>>>(src, dst, bkt_cursor, pairs, E);
  k_scanbkt  <<<1, 512, 0, stream>>>(bkt_cursor, NB, bucket_base, row_ptr, N);
  k_build    <<<NB, 1024, 0, stream>>>(bkt_cursor, bucket_base, pairs, row_ptr, csr_src, N);

  int gRows = (N+63)/64;
  int gWave = (N+3)/4;
  int gRows42 = (N+127)/128;
  // layer 0
  k_gemm128T<false><<<gRows,256,0,stream>>>(inputs, W0, al0, ar0, Fb, el, er, N);
  k_agg128 <<<gWave,256,0,stream>>>((const uint32*)Fb, el, er, row_ptr, csr_src, bufH, N);
  // layer 1
  k_gemm128T<true><<<gRows,256,0,stream>>>(bufH, W1, al1, ar1, Fb, el, er, N);
  k_agg128 <<<gWave,256,0,stream>>>((const uint32*)Fb, el, er, row_ptr, csr_src, bufH, N);
  // layer 2
  k_gemm42 <<<gRows42,256,0,stream>>>(bufH, W2, al2, ar2, Fb40, el2, er2, N);
  k_agg40  <<<gWave,256,0,stream>>>(Fb40, el2, er2, row_ptr, csr_src, (float*)d_out, N);
}

// Round 8
// 350.827 us; speedup vs baseline: 3.0016x; 1.1597x over previous
//
#include <hip/hip_runtime.h>
#include <math.h>

typedef unsigned int uint32;
typedef unsigned short ushort;
typedef __attribute__((ext_vector_type(8))) short short8;
typedef __attribute__((ext_vector_type(4))) float f32x4;

__device__ inline uint32 bf16rn(float x){
  uint32 b = __float_as_uint(x);
  return (b + 0x7fffu + ((b>>16)&1u)) >> 16;
}
__device__ inline float bf16lo(uint32 v){ return __uint_as_float(v<<16); }
__device__ inline float bf16hi(uint32 v){ return __uint_as_float(v & 0xffff0000u); }

#define BKT_SHIFT 9            // 512 nodes per bucket
#define BKTCAP 12288           // per-bucket record capacity
#define PCHUNK 8192            // edges per partition block
#define FB40S 64               // padded row stride for layer-2 feat

// ---------------- pass 1: LDS-staged bucket partition ----------------
__global__ __launch_bounds__(256) void k_partition(const int* __restrict__ src, const int* __restrict__ dst,
                        int* __restrict__ bkt_cursor, uint32* __restrict__ pairs, int E){
  __shared__ int cnt[512];
  __shared__ int base[512];
  int t = threadIdx.x;
  int blockBase = blockIdx.x * PCHUNK;
  for (int i=t; i<512; i+=256) cnt[i]=0;
  __syncthreads();
  #pragma unroll
  for (int i=0; i<PCHUNK/1024; i++){
    int e0 = blockBase + (i*256 + t)*4;
    if (e0+3 < E){
      int4 d4 = *(const int4*)&dst[e0];
      atomicAdd(&cnt[d4.x>>BKT_SHIFT],1);
      atomicAdd(&cnt[d4.y>>BKT_SHIFT],1);
      atomicAdd(&cnt[d4.z>>BKT_SHIFT],1);
      atomicAdd(&cnt[d4.w>>BKT_SHIFT],1);
    } else {
      for (int e=e0; e<E && e<e0+4; e++) atomicAdd(&cnt[dst[e]>>BKT_SHIFT],1);
    }
  }
  __syncthreads();
  for (int i=t; i<512; i+=256){
    int c = cnt[i];
    base[i] = c ? atomicAdd(&bkt_cursor[i], c) : 0;
    cnt[i] = 0;
  }
  __syncthreads();
  #pragma unroll
  for (int i=0; i<PCHUNK/1024; i++){
    int e0 = blockBase + (i*256 + t)*4;
    if (e0+3 < E){
      int4 s4 = *(const int4*)&src[e0];
      int4 d4 = *(const int4*)&dst[e0];
      int bx, pos;
      bx=d4.x>>BKT_SHIFT; pos=base[bx]+atomicAdd(&cnt[bx],1); if(pos<BKTCAP) pairs[(size_t)bx*BKTCAP+pos]=(uint32)s4.x|((uint32)(d4.x&511)<<22);
      bx=d4.y>>BKT_SHIFT; pos=base[bx]+atomicAdd(&cnt[bx],1); if(pos<BKTCAP) pairs[(size_t)bx*BKTCAP+pos]=(uint32)s4.y|((uint32)(d4.y&511)<<22);
      bx=d4.z>>BKT_SHIFT; pos=base[bx]+atomicAdd(&cnt[bx],1); if(pos<BKTCAP) pairs[(size_t)bx*BKTCAP+pos]=(uint32)s4.z|((uint32)(d4.z&511)<<22);
      bx=d4.w>>BKT_SHIFT; pos=base[bx]+atomicAdd(&cnt[bx],1); if(pos<BKTCAP) pairs[(size_t)bx*BKTCAP+pos]=(uint32)s4.w|((uint32)(d4.w&511)<<22);
    } else {
      for (int e=e0; e<E && e<e0+4; e++){
        int s=src[e], d=dst[e];
        int bx=d>>BKT_SHIFT; int pos=base[bx]+atomicAdd(&cnt[bx],1);
        if(pos<BKTCAP) pairs[(size_t)bx*BKTCAP+pos]=(uint32)s|((uint32)(d&511)<<22);
      }
    }
  }
}

// ---------------- pass 2: scan bucket totals ----------------
__global__ __launch_bounds__(512) void k_scanbkt(const int* __restrict__ bkt_cursor, int nb,
                      int* __restrict__ bucket_base, int* __restrict__ row_ptr, int N){
  __shared__ int sc[512];
  int t = threadIdx.x;
  int v = (t<nb) ? min(bkt_cursor[t], BKTCAP) : 0;
  sc[t]=v; __syncthreads();
  int x=v;
  for (int off=1; off<512; off<<=1){
    int y=(t>=off)? sc[t-off]:0;
    __syncthreads();
    x+=y; sc[t]=x;
    __syncthreads();
  }
  if (t<nb) bucket_base[t] = x - v;
  if (t==511) row_ptr[N] = x;
}

// ---------------- pass 3: per-bucket CSR build ----------------
__global__ __launch_bounds__(1024) void k_build(const int* __restrict__ bkt_cursor,
                        const int* __restrict__ bucket_base, const uint32* __restrict__ pairs,
                        int* __restrict__ row_ptr, int* __restrict__ csr_src, int N){
  __shared__ int hist[512];
  __shared__ int sc[512];
  __shared__ int cur[512];
  int b = blockIdx.x;
  int t = threadIdx.x;
  int cnt = bkt_cursor[b]; if (cnt > BKTCAP) cnt = BKTCAP;
  int base = bucket_base[b];
  const uint32* p = pairs + (size_t)b*BKTCAP;
  if (t<512) hist[t]=0;
  __syncthreads();
  for (int i=t; i<cnt; i+=1024) atomicAdd(&hist[p[i]>>22], 1);
  __syncthreads();
  int v = (t<512)? hist[t] : 0;
  if (t<512) sc[t]=v;
  __syncthreads();
  int x=v;
  for (int off=1; off<512; off<<=1){
    int y = (t<512 && t>=off)? sc[t-off] : 0;
    __syncthreads();
    if (t<512){ x+=y; sc[t]=x; }
    __syncthreads();
  }
  if (t<512){
    int excl = x - v;
    int gnode = (b<<BKT_SHIFT) + t;
    if (gnode < N) row_ptr[gnode] = base + excl;
    cur[t] = excl;
  }
  __syncthreads();
  for (int i=t; i<cnt; i+=1024){
    uint32 e = p[i];
    int pos = atomicAdd(&cur[e>>22], 1);
    csr_src[base + pos] = (int)(e & 0x3FFFFFu);
  }
}

// ---------------- MFMA GEMM [N,128]x[128,128] -> bf16 F + fused el/er ----------------
// D[i=col][j=row] = sum_k WT[col][k] * A[row][k]; 64 rows/block, 4 waves x 16 rows.
// LDS: WT bf16 [128][128] + A bf16 [64][128], both XOR-swizzled (byte ^= (row&7)<<4).
template<bool BF16A>
__global__ __launch_bounds__(256) void k_gemm128_mfma(const void* __restrict__ Av, const float* __restrict__ W,
                        const float* __restrict__ al, const float* __restrict__ ar,
                        ushort* __restrict__ Fb, float* __restrict__ el, float* __restrict__ er, int N){
  __shared__ __align__(16) ushort Wlds[128*128];
  __shared__ __align__(16) ushort Alds[64*128];
  __shared__ float sal[128], sar[128];
  int t = threadIdx.x;
  int rowBase = blockIdx.x*64;
  // ---- stage W -> WT bf16 (k-pairs packed as uint32)
  for (int i=t; i<8192; i+=256){
    int col = i & 127;
    int k2  = (i >> 7) * 2;
    float w0 = W[(size_t)k2*128 + col];
    float w1 = W[(size_t)(k2+1)*128 + col];
    uint32 pk = bf16rn(w0) | (bf16rn(w1)<<16);
    int byte = col*256 + k2*2;
    byte ^= (col&7)<<4;
    *(uint32*)((char*)Wlds + byte) = pk;
  }
  if (t < 128){ sal[t] = al[t]; sar[t] = ar[t]; }
  // ---- stage A tile (64 rows x 128 k) bf16
  {
    int row = t>>2, k0 = (t&3)*32;
    int grow = rowBase + row;
    uint32 pk[16];
    if (grow < N){
      if constexpr (BF16A){
        const ushort* Ab = (const ushort*)Av;
        const uint4* ap = (const uint4*)(Ab + (size_t)grow*128 + k0);
        #pragma unroll
        for (int q=0;q<4;q++){ uint4 u = ap[q]; pk[q*4]=u.x; pk[q*4+1]=u.y; pk[q*4+2]=u.z; pk[q*4+3]=u.w; }
      } else {
        const float* Af = (const float*)Av;
        #pragma unroll
        for (int j=0;j<16;j++){
          float2 v = *(const float2*)(Af + (size_t)grow*128 + k0 + j*2);
          pk[j] = bf16rn(v.x) | (bf16rn(v.y)<<16);
        }
      }
    } else {
      #pragma unroll
      for (int j=0;j<16;j++) pk[j]=0u;
    }
    #pragma unroll
    for (int q=0;q<4;q++){
      int byte = row*256 + (k0 + q*8)*2;
      byte ^= (row&7)<<4;
      *(uint4*)((char*)Alds + byte) = make_uint4(pk[q*4],pk[q*4+1],pk[q*4+2],pk[q*4+3]);
    }
  }
  __syncthreads();
  // ---- MFMA main loop
  int wid = t>>6, lane = t&63;
  int strip = wid*16;
  int lrow = lane & 15;
  int lk   = (lane>>4)*8;
  int swz  = (lrow&7)<<4;
  f32x4 acc[8];
  #pragma unroll
  for (int tc=0; tc<8; tc++) acc[tc] = (f32x4){0.f,0.f,0.f,0.f};
  #pragma unroll
  for (int kstep=0; kstep<4; kstep++){
    int kb = (kstep*32 + lk)*2;
    short8 bfrag = *(const short8*)((const char*)Alds + (((strip+lrow)*256 + kb) ^ swz));
    #pragma unroll
    for (int tc=0; tc<8; tc++){
      short8 afrag = *(const short8*)((const char*)Wlds + (((tc*16+lrow)*256 + kb) ^ swz));
      acc[tc] = __builtin_amdgcn_mfma_f32_16x16x32_bf16(afrag, bfrag, acc[tc], 0, 0, 0);
    }
  }
  // ---- epilogue: bf16 feat store + per-head el/er
  int row = rowBase + strip + lrow;
  int cq = (lane>>4)*4;
  #pragma unroll
  for (int tc=0; tc<8; tc++){
    if (row < N){
      uint32 u0 = bf16rn(acc[tc][0]) | (bf16rn(acc[tc][1])<<16);
      uint32 u1 = bf16rn(acc[tc][2]) | (bf16rn(acc[tc][3])<<16);
      *(uint2*)(Fb + (size_t)row*128 + tc*16 + cq) = make_uint2(u0,u1);
    }
  }
  float hl[4] = {0.f,0.f,0.f,0.f};
  float hr[4] = {0.f,0.f,0.f,0.f};
  #pragma unroll
  for (int tc=0; tc<8; tc++){
    int cbase = tc*16 + cq;
    int h = tc>>1;
    #pragma unroll
    for (int r=0;r<4;r++){
      hl[h] = fmaf(acc[tc][r], sal[cbase+r], hl[h]);
      hr[h] = fmaf(acc[tc][r], sar[cbase+r], hr[h]);
    }
  }
  #pragma unroll
  for (int h=0;h<4;h++){
    hl[h] += __shfl_xor(hl[h],16); hl[h] += __shfl_xor(hl[h],32);
    hr[h] += __shfl_xor(hr[h],16); hr[h] += __shfl_xor(hr[h],32);
  }
  if (lane < 16 && row < N){
    *(float4*)&el[(size_t)row*4] = make_float4(hl[0],hl[1],hl[2],hl[3]);
    *(float4*)&er[(size_t)row*4] = make_float4(hr[0],hr[1],hr[2],hr[3]);
  }
}

// ---------------- fused edge-softmax + aggregation (H=4,D=32) ----------------
__global__ __launch_bounds__(256) void k_agg128(const uint32* __restrict__ Fu, const float* __restrict__ el,
                         const float* __restrict__ er, const int* __restrict__ row_ptr,
                         const int* __restrict__ csr_src, ushort* __restrict__ out, int N){
  __shared__ float wlds[4][272];
  int t = threadIdx.x;
  int lane = t & 63;
  int wv = t >> 6;
  int node = (blockIdx.x*blockDim.x + t)>>6;
  if (__builtin_amdgcn_readfirstlane(node) >= N) return;
  int h = lane>>4;
  int i0 = lane & 15;
  float erv = er[(size_t)node*4+h];
  int beg = row_ptr[node], end = row_ptr[node+1];
  int ubeg = __builtin_amdgcn_readfirstlane(beg);
  int uend = __builtin_amdgcn_readfirstlane(end);
  int udeg = uend - ubeg;
  int sv = (lane < udeg) ? csr_src[ubeg+lane] : 0;
  int sn[4]; float evv[4];
  #pragma unroll
  for (int j=0;j<4;j++) sn[j] = __shfl(sv, i0 + 16*j);
  #pragma unroll
  for (int j=0;j<4;j++) evv[j] = el[(size_t)sn[j]*4+h];
  float w4[4];
  #pragma unroll
  for (int j=0;j<4;j++){
    float ev = evv[j] + erv;
    ev = ev>0.f ? ev : 0.2f*ev;
    w4[j] = (i0 + 16*j < udeg) ? __expf(ev) : 0.f;
  }
  float dsum = (w4[0]+w4[1]) + (w4[2]+w4[3]);
  dsum += __shfl_xor(dsum, 1);
  dsum += __shfl_xor(dsum, 2);
  dsum += __shfl_xor(dsum, 4);
  dsum += __shfl_xor(dsum, 8);
  int wb = h*68 + i0;
  wlds[wv][wb   ] = w4[0];
  wlds[wv][wb+16] = w4[1];
  wlds[wv][wb+32] = w4[2];
  wlds[wv][wb+48] = w4[3];
  const int* sp = csr_src + ubeg;
  const float* wp = &wlds[wv][h*68];
  float acc0=0.f, acc1=0.f;
  int nm = udeg > 64 ? 64 : udeg;
  uint32 vb[8];
  #pragma unroll
  for (int k=0;k<8;k++) vb[k] = (k<nm) ? Fu[(size_t)sp[k]*64 + lane] : 0u;
  int i=0;
  for (; i+16<=nm; i+=8){
    uint32 vn[8];
    #pragma unroll
    for (int k=0;k<8;k++) vn[k] = Fu[(size_t)sp[i+8+k]*64 + lane];
    #pragma unroll
    for (int k=0;k<8;k++){
      float wi = wp[i+k];
      acc0 = fmaf(wi, bf16lo(vb[k]), acc0);
      acc1 = fmaf(wi, bf16hi(vb[k]), acc1);
    }
    #pragma unroll
    for (int k=0;k<8;k++) vb[k]=vn[k];
  }
  {
    int lim = nm - i; if (lim > 8) lim = 8;
    #pragma unroll
    for (int k=0;k<8;k++) if (k<lim){
      float wi = wp[i+k];
      acc0 = fmaf(wi, bf16lo(vb[k]), acc0);
      acc1 = fmaf(wi, bf16hi(vb[k]), acc1);
    }
    for (int e=i+8; e<nm; e++){
      float wi = wp[e];
      uint32 v = Fu[(size_t)sp[e]*64 + lane];
      acc0 = fmaf(wi, bf16lo(v), acc0);
      acc1 = fmaf(wi, bf16hi(v), acc1);
    }
  }
  if (udeg > 64){
    for (int e=64; e<udeg; e++){
      int s = sp[e];
      float x = el[(size_t)s*4+h] + erv;
      x = x>0.f?x:0.2f*x; x=__expf(x);
      uint32 v = Fu[(size_t)s*64+lane];
      dsum += x;
      acc0 = fmaf(x, bf16lo(v), acc0);
      acc1 = fmaf(x, bf16hi(v), acc1);
    }
  }
  float inv = 1.0f/dsum;
  float o0 = acc0*inv, o1 = acc1*inv;
  o0 = o0>0.f ? o0 : expm1f(o0);
  o1 = o1>0.f ? o1 : expm1f(o1);
  uint32 uo = bf16rn(o0) | (bf16rn(o1)<<16);
  *(uint32*)(out + (size_t)node*128 + lane*2) = uo;
}

// ---------------- layer-2: tiled GEMM [N,128(bf16)]x[128,40+2] -> bf16 Fb40(stride 64), el2, er2 ----------------
__global__ __launch_bounds__(256) void k_gemm42(const ushort* __restrict__ A, const float* __restrict__ W,
                        const float* __restrict__ al, const float* __restrict__ ar,
                        ushort* __restrict__ Fb, float* __restrict__ el, float* __restrict__ er, int N){
  __shared__ float wfull[128*48];
  __shared__ float hs[32][132];
  int t = threadIdx.x;
  int rowBase = blockIdx.x*128;
  for (int i=t; i<1280; i+=256){
    float4 v = *(const float4*)&W[i*4];
    int g = i*4;
    *(float4*)&wfull[(g/40)*48 + (g%40)] = v;
  }
  {
    int k = t & 127;
    const float* wrow = W + k*40;
    const float* a = (t < 128) ? al : ar;
    float s = 0.f;
    #pragma unroll
    for (int c=0;c<40;c++) s += wrow[c]*a[c];
    if (t < 128){
      wfull[k*48+40] = s;
      wfull[k*48+42] = 0.f; wfull[k*48+43] = 0.f; wfull[k*48+44] = 0.f;
    } else {
      wfull[k*48+41] = s;
      wfull[k*48+45] = 0.f; wfull[k*48+46] = 0.f; wfull[k*48+47] = 0.f;
    }
  }
  int c0 = (t&7)*6;
  int r0 = (t>>3)*4;
  float acc[4][6] = {};
  for (int kc=0; kc<128; kc+=32){
    {
      int row = t>>1; int kk0 = (t&1)*16;
      int grow = rowBase + row;
      if (grow < N){
        uint4 u0 = *(const uint4*)&A[(size_t)grow*128 + kc + kk0];
        uint4 u1 = *(const uint4*)&A[(size_t)grow*128 + kc + kk0 + 8];
        hs[kk0+ 0][row]=bf16lo(u0.x); hs[kk0+ 1][row]=bf16hi(u0.x);
        hs[kk0+ 2][row]=bf16lo(u0.y); hs[kk0+ 3][row]=bf16hi(u0.y);
        hs[kk0+ 4][row]=bf16lo(u0.z); hs[kk0+ 5][row]=bf16hi(u0.z);
        hs[kk0+ 6][row]=bf16lo(u0.w); hs[kk0+ 7][row]=bf16hi(u0.w);
        hs[kk0+ 8][row]=bf16lo(u1.x); hs[kk0+ 9][row]=bf16hi(u1.x);
        hs[kk0+10][row]=bf16lo(u1.y); hs[kk0+11][row]=bf16hi(u1.y);
        hs[kk0+12][row]=bf16lo(u1.z); hs[kk0+13][row]=bf16hi(u1.z);
        hs[kk0+14][row]=bf16lo(u1.w); hs[kk0+15][row]=bf16hi(u1.w);
      } else {
        #pragma unroll
        for (int j=0;j<16;j++) hs[kk0+j][row]=0.f;
      }
    }
    __syncthreads();
    #pragma unroll
    for (int k=0;k<32;k++){
      float4 av = *(const float4*)&hs[k][r0];
      const float* wp = &wfull[(kc+k)*48 + c0];
      float2 b01 = *(const float2*)&wp[0];
      float2 b23 = *(const float2*)&wp[2];
      float2 b45 = *(const float2*)&wp[4];
      float a4[4] = {av.x,av.y,av.z,av.w};
      float b6[6] = {b01.x,b01.y,b23.x,b23.y,b45.x,b45.y};
      #pragma unroll
      for (int r=0;r<4;r++)
        #pragma unroll
        for (int c=0;c<6;c++)
          acc[r][c] = fmaf(a4[r], b6[c], acc[r][c]);
    }
    __syncthreads();
  }
  #pragma unroll
  for (int r=0;r<4;r++){
    int row = rowBase + r0 + r;
    if (row >= N) break;
    if (c0 < 40){
      #pragma unroll
      for (int j=0;j<6;j+=2){
        int col = c0 + j;
        if (col < 40){
          uint32 u = bf16rn(acc[r][j]) | (bf16rn(acc[r][j+1])<<16);
          *(uint32*)(Fb + (size_t)row*FB40S + col) = u;
        }
      }
      if (c0 == 36){ el[row] = acc[r][4]; er[row] = acc[r][5]; }
    }
  }
}

// ---------------- final aggregation (H=1,D=40) + log_softmax ----------------
__global__ __launch_bounds__(256) void k_agg40(const ushort* __restrict__ Fb, const float* __restrict__ el,
                       const float* __restrict__ er, const int* __restrict__ row_ptr,
                       const int* __restrict__ csr_src, float* __restrict__ out, int N){
  __shared__ float wlds[4][64];
  int t = threadIdx.x;
  int lane = t & 63;
  int wv = t >> 6;
  int node = (blockIdx.x*blockDim.x + t)>>6;
  if (__builtin_amdgcn_readfirstlane(node) >= N) return;
  bool act = lane<40;
  int l40 = act ? lane : 0;
  float erv = er[node];
  int beg = row_ptr[node], end = row_ptr[node+1];
  int ubeg = __builtin_amdgcn_readfirstlane(beg);
  int uend = __builtin_amdgcn_readfirstlane(end);
  int udeg = uend - ubeg;
  int sv = (lane < udeg) ? csr_src[ubeg+lane] : 0;
  float w = 0.f;
  if (lane < udeg){
    float ev = el[sv] + erv;
    ev = ev>0.f ? ev : 0.2f*ev;
    w = __expf(ev);
  }
  float dsum = w;
  dsum += __shfl_xor(dsum, 1);
  dsum += __shfl_xor(dsum, 2);
  dsum += __shfl_xor(dsum, 4);
  dsum += __shfl_xor(dsum, 8);
  dsum += __shfl_xor(dsum, 16);
  dsum += __shfl_xor(dsum, 32);
  wlds[wv][lane] = w;
  const int* sp = csr_src + ubeg;
  float acc=0.f;
  int nm = udeg > 64 ? 64 : udeg;
  ushort fb8[8];
  #pragma unroll
  for (int k=0;k<8;k++) fb8[k] = (k<nm) ? Fb[(size_t)sp[k]*FB40S + l40] : (ushort)0;
  int i=0;
  for (; i+16<=nm; i+=8){
    ushort fn[8];
    #pragma unroll
    for (int k=0;k<8;k++) fn[k] = Fb[(size_t)sp[i+8+k]*FB40S + l40];
    #pragma unroll
    for (int k=0;k<8;k++){
      float wi = wlds[wv][i+k];
      acc = fmaf(wi, __uint_as_float(((uint32)fb8[k])<<16), acc);
    }
    #pragma unroll
    for (int k=0;k<8;k++) fb8[k]=fn[k];
  }
  {
    int lim = nm - i; if (lim > 8) lim = 8;
    #pragma unroll
    for (int k=0;k<8;k++) if (k<lim){
      float wi = wlds[wv][i+k];
      acc = fmaf(wi, __uint_as_float(((uint32)fb8[k])<<16), acc);
    }
    for (int e=i+8; e<nm; e++){
      float wi = wlds[wv][e];
      ushort f = Fb[(size_t)sp[e]*FB40S + l40];
      acc = fmaf(wi, __uint_as_float(((uint32)f)<<16), acc);
    }
  }
  if (udeg > 64){
    for (int e=64; e<udeg; e++){
      int s = sp[e];
      float x = el[s] + erv;
      x = x>0.f?x:0.2f*x; x=__expf(x);
      ushort f = Fb[(size_t)s*FB40S + l40];
      dsum += x;
      acc = fmaf(x, __uint_as_float(((uint32)f)<<16), acc);
    }
  }
  float logit = acc/dsum;
  float m = act ? logit : -INFINITY;
  for (int off=32; off; off>>=1) m = fmaxf(m, __shfl_xor(m, off));
  float ex = act ? expf(logit - m) : 0.f;
  float ssum = ex;
  for (int off=32; off; off>>=1) ssum += __shfl_xor(ssum, off);
  if (act) out[(size_t)node*40 + lane] = logit - m - logf(ssum);
}

extern "C" void kernel_launch(void* const* d_in, const int* in_sizes, int n_in,
                              void* d_out, int out_size, void* d_ws, size_t ws_size,
                              hipStream_t stream){
  const float* inputs = (const float*)d_in[0];
  const float* W0  = (const float*)d_in[1];
  const float* al0 = (const float*)d_in[2];
  const float* ar0 = (const float*)d_in[3];
  const float* W1  = (const float*)d_in[4];
  const float* al1 = (const float*)d_in[5];
  const float* ar1 = (const float*)d_in[6];
  const float* W2  = (const float*)d_in[7];
  const float* al2 = (const float*)d_in[8];
  const float* ar2 = (const float*)d_in[9];
  const int* src = (const int*)d_in[10];
  const int* dst = (const int*)d_in[11];
  int N = in_sizes[0]/128;
  int E = in_sizes[10];
  int NB = (N + (1<<BKT_SHIFT) - 1) >> BKT_SHIFT;

  char* p = (char*)d_ws;
  auto carve = [&](size_t bytes)->char*{ char* q=p; p += ((bytes+255)/256)*256; return q; };
  ushort* Fb   = (ushort*)carve((size_t)N*128*2);     // bf16 feat
  ushort* Fb40 = (ushort*)carve((size_t)N*FB40S*2);   // bf16 layer-2 feat (padded stride)
  ushort* bufH = (ushort*)carve((size_t)N*128*2);     // bf16 hidden; pairs alias this during CSR build
  float* el  = (float*)carve((size_t)N*4*4);
  float* er  = (float*)carve((size_t)N*4*4);
  float* el2 = (float*)carve((size_t)N*4);
  float* er2 = (float*)carve((size_t)N*4);
  int* bkt_cursor  = (int*)carve((size_t)NB*4);       // zero-init
  int* bucket_base = (int*)carve((size_t)NB*4);
  int* row_ptr = (int*)carve((size_t)(N+1)*4);
  int* csr_src = (int*)carve((size_t)E*4);

  uint32* pairs = (uint32*)bufH;                      // NB*BKTCAP*4 = 9.6 MB < 25.6 MB

  hipMemsetAsync(bkt_cursor, 0, (size_t)NB*4, stream);
  int nPB = (E + PCHUNK - 1) / PCHUNK;
  k_partition<<<nPB, 256, 0, stream>>>(src, dst, bkt_cursor, pairs, E);
  k_scanbkt  <<<1, 512, 0, stream>>>(bkt_cursor, NB, bucket_base, row_ptr, N);
  k_build    <<<NB, 1024, 0, stream>>>(bkt_cursor, bucket_base, pairs, row_ptr, csr_src, N);

  int gRows = (N+63)/64;
  int gWave = (N+3)/4;
  int gRows42 = (N+127)/128;
  // layer 0
  k_gemm128_mfma<false><<<gRows,256,0,stream>>>(inputs, W0, al0, ar0, Fb, el, er, N);
  k_agg128 <<<gWave,256,0,stream>>>((const uint32*)Fb, el, er, row_ptr, csr_src, bufH, N);
  // layer 1
  k_gemm128_mfma<true><<<gRows,256,0,stream>>>(bufH, W1, al1, ar1, Fb, el, er, N);
  k_agg128 <<<gWave,256,0,stream>>>((const uint32*)Fb, el, er, row_ptr, csr_src, bufH, N);
  // layer 2
  k_gemm42 <<<gRows42,256,0,stream>>>(bufH, W2, al2, ar2, Fb40, el2, er2, N);
  k_agg40  <<<gWave,256,0,stream>>>(Fb40, el2, er2, row_ptr, csr_src, (float*)d_out, N);
}

// Round 9
// 347.748 us; speedup vs baseline: 3.0281x; 1.0089x over previous
//
#include <hip/hip_runtime.h>
#include <math.h>

typedef unsigned int uint32;
typedef unsigned short ushort;
typedef __attribute__((ext_vector_type(8))) short short8;
typedef __attribute__((ext_vector_type(4))) float f32x4;

__device__ inline uint32 bf16rn(float x){
  uint32 b = __float_as_uint(x);
  return (b + 0x7fffu + ((b>>16)&1u)) >> 16;
}
__device__ inline float bf16lo(uint32 v){ return __uint_as_float(v<<16); }
__device__ inline float bf16hi(uint32 v){ return __uint_as_float(v & 0xffff0000u); }

#define BKT_SHIFT 9            // 512 nodes per bucket
#define BKTCAP 12288           // per-bucket record capacity
#define PCHUNK 4096            // edges per partition block (415 blocks -> ~1.6/CU)
#define FB40S 64               // padded row stride for layer-2 feat

// ---------------- pass 1: LDS-staged bucket partition ----------------
__global__ __launch_bounds__(256) void k_partition(const int* __restrict__ src, const int* __restrict__ dst,
                        int* __restrict__ bkt_cursor, uint32* __restrict__ pairs, int E){
  __shared__ int cnt[512];
  __shared__ int base[512];
  int t = threadIdx.x;
  int blockBase = blockIdx.x * PCHUNK;
  for (int i=t; i<512; i+=256) cnt[i]=0;
  __syncthreads();
  #pragma unroll
  for (int i=0; i<PCHUNK/1024; i++){
    int e0 = blockBase + (i*256 + t)*4;
    if (e0+3 < E){
      int4 d4 = *(const int4*)&dst[e0];
      atomicAdd(&cnt[d4.x>>BKT_SHIFT],1);
      atomicAdd(&cnt[d4.y>>BKT_SHIFT],1);
      atomicAdd(&cnt[d4.z>>BKT_SHIFT],1);
      atomicAdd(&cnt[d4.w>>BKT_SHIFT],1);
    } else {
      for (int e=e0; e<E && e<e0+4; e++) atomicAdd(&cnt[dst[e]>>BKT_SHIFT],1);
    }
  }
  __syncthreads();
  for (int i=t; i<512; i+=256){
    int c = cnt[i];
    base[i] = c ? atomicAdd(&bkt_cursor[i], c) : 0;
    cnt[i] = 0;
  }
  __syncthreads();
  #pragma unroll
  for (int i=0; i<PCHUNK/1024; i++){
    int e0 = blockBase + (i*256 + t)*4;
    if (e0+3 < E){
      int4 s4 = *(const int4*)&src[e0];
      int4 d4 = *(const int4*)&dst[e0];
      int bx, pos;
      bx=d4.x>>BKT_SHIFT; pos=base[bx]+atomicAdd(&cnt[bx],1); if(pos<BKTCAP) pairs[(size_t)bx*BKTCAP+pos]=(uint32)s4.x|((uint32)(d4.x&511)<<22);
      bx=d4.y>>BKT_SHIFT; pos=base[bx]+atomicAdd(&cnt[bx],1); if(pos<BKTCAP) pairs[(size_t)bx*BKTCAP+pos]=(uint32)s4.y|((uint32)(d4.y&511)<<22);
      bx=d4.z>>BKT_SHIFT; pos=base[bx]+atomicAdd(&cnt[bx],1); if(pos<BKTCAP) pairs[(size_t)bx*BKTCAP+pos]=(uint32)s4.z|((uint32)(d4.z&511)<<22);
      bx=d4.w>>BKT_SHIFT; pos=base[bx]+atomicAdd(&cnt[bx],1); if(pos<BKTCAP) pairs[(size_t)bx*BKTCAP+pos]=(uint32)s4.w|((uint32)(d4.w&511)<<22);
    } else {
      for (int e=e0; e<E && e<e0+4; e++){
        int s=src[e], d=dst[e];
        int bx=d>>BKT_SHIFT; int pos=base[bx]+atomicAdd(&cnt[bx],1);
        if(pos<BKTCAP) pairs[(size_t)bx*BKTCAP+pos]=(uint32)s|((uint32)(d&511)<<22);
      }
    }
  }
}

// ---------------- pass 2: per-bucket CSR build (scan of bucket totals folded in) ----------------
__global__ __launch_bounds__(1024) void k_build(const int* __restrict__ bkt_cursor, int nb,
                        const uint32* __restrict__ pairs,
                        int* __restrict__ row_ptr, int* __restrict__ csr_src, int N){
  __shared__ int bscan[256];
  __shared__ int hist[512];
  __shared__ int sc[512];
  __shared__ int cur[512];
  int b = blockIdx.x;
  int t = threadIdx.x;
  // ---- scan bucket totals (nb <= 256) to get this bucket's base
  int v0 = (t<256 && t<nb) ? min(bkt_cursor[t], BKTCAP) : 0;
  if (t<256) bscan[t] = v0;
  __syncthreads();
  int x0 = v0;
  for (int off=1; off<256; off<<=1){
    int y = (t<256 && t>=off) ? bscan[t-off] : 0;
    __syncthreads();
    if (t<256){ x0 += y; bscan[t] = x0; }
    __syncthreads();
  }
  int base = (b==0) ? 0 : bscan[b-1];
  if (b==0 && t==0) row_ptr[N] = bscan[nb-1];
  int cnt = bkt_cursor[b]; if (cnt > BKTCAP) cnt = BKTCAP;
  const uint32* p = pairs + (size_t)b*BKTCAP;
  // ---- per-node histogram
  if (t<512) hist[t]=0;
  __syncthreads();
  for (int i=t; i<cnt; i+=1024) atomicAdd(&hist[p[i]>>22], 1);
  __syncthreads();
  int v = (t<512)? hist[t] : 0;
  if (t<512) sc[t]=v;
  __syncthreads();
  int x=v;
  for (int off=1; off<512; off<<=1){
    int y = (t<512 && t>=off)? sc[t-off] : 0;
    __syncthreads();
    if (t<512){ x+=y; sc[t]=x; }
    __syncthreads();
  }
  if (t<512){
    int excl = x - v;
    int gnode = (b<<BKT_SHIFT) + t;
    if (gnode < N) row_ptr[gnode] = base + excl;
    cur[t] = excl;
  }
  __syncthreads();
  for (int i=t; i<cnt; i+=1024){
    uint32 e = p[i];
    int pos = atomicAdd(&cur[e>>22], 1);
    csr_src[base + pos] = (int)(e & 0x3FFFFFu);
  }
}

// ---------------- MFMA GEMM [N,128]x[128,128] -> bf16 F + fused el/er ----------------
template<bool BF16A>
__global__ __launch_bounds__(256) void k_gemm128_mfma(const void* __restrict__ Av, const float* __restrict__ W,
                        const float* __restrict__ al, const float* __restrict__ ar,
                        ushort* __restrict__ Fb, float* __restrict__ el, float* __restrict__ er, int N){
  __shared__ __align__(16) ushort Wlds[128*128];
  __shared__ __align__(16) ushort Alds[64*128];
  __shared__ float sal[128], sar[128];
  int t = threadIdx.x;
  int rowBase = blockIdx.x*64;
  for (int i=t; i<8192; i+=256){
    int col = i & 127;
    int k2  = (i >> 7) * 2;
    float w0 = W[(size_t)k2*128 + col];
    float w1 = W[(size_t)(k2+1)*128 + col];
    uint32 pk = bf16rn(w0) | (bf16rn(w1)<<16);
    int byte = col*256 + k2*2;
    byte ^= (col&7)<<4;
    *(uint32*)((char*)Wlds + byte) = pk;
  }
  if (t < 128){ sal[t] = al[t]; sar[t] = ar[t]; }
  {
    int row = t>>2, k0 = (t&3)*32;
    int grow = rowBase + row;
    uint32 pk[16];
    if (grow < N){
      if constexpr (BF16A){
        const ushort* Ab = (const ushort*)Av;
        const uint4* ap = (const uint4*)(Ab + (size_t)grow*128 + k0);
        #pragma unroll
        for (int q=0;q<4;q++){ uint4 u = ap[q]; pk[q*4]=u.x; pk[q*4+1]=u.y; pk[q*4+2]=u.z; pk[q*4+3]=u.w; }
      } else {
        const float* Af = (const float*)Av;
        #pragma unroll
        for (int j=0;j<16;j++){
          float2 v = *(const float2*)(Af + (size_t)grow*128 + k0 + j*2);
          pk[j] = bf16rn(v.x) | (bf16rn(v.y)<<16);
        }
      }
    } else {
      #pragma unroll
      for (int j=0;j<16;j++) pk[j]=0u;
    }
    #pragma unroll
    for (int q=0;q<4;q++){
      int byte = row*256 + (k0 + q*8)*2;
      byte ^= (row&7)<<4;
      *(uint4*)((char*)Alds + byte) = make_uint4(pk[q*4],pk[q*4+1],pk[q*4+2],pk[q*4+3]);
    }
  }
  __syncthreads();
  int wid = t>>6, lane = t&63;
  int strip = wid*16;
  int lrow = lane & 15;
  int lk   = (lane>>4)*8;
  int swz  = (lrow&7)<<4;
  f32x4 acc[8];
  #pragma unroll
  for (int tc=0; tc<8; tc++) acc[tc] = (f32x4){0.f,0.f,0.f,0.f};
  #pragma unroll
  for (int kstep=0; kstep<4; kstep++){
    int kb = (kstep*32 + lk)*2;
    short8 bfrag = *(const short8*)((const char*)Alds + (((strip+lrow)*256 + kb) ^ swz));
    #pragma unroll
    for (int tc=0; tc<8; tc++){
      short8 afrag = *(const short8*)((const char*)Wlds + (((tc*16+lrow)*256 + kb) ^ swz));
      acc[tc] = __builtin_amdgcn_mfma_f32_16x16x32_bf16(afrag, bfrag, acc[tc], 0, 0, 0);
    }
  }
  int row = rowBase + strip + lrow;
  int cq = (lane>>4)*4;
  #pragma unroll
  for (int tc=0; tc<8; tc++){
    if (row < N){
      uint32 u0 = bf16rn(acc[tc][0]) | (bf16rn(acc[tc][1])<<16);
      uint32 u1 = bf16rn(acc[tc][2]) | (bf16rn(acc[tc][3])<<16);
      *(uint2*)(Fb + (size_t)row*128 + tc*16 + cq) = make_uint2(u0,u1);
    }
  }
  float hl[4] = {0.f,0.f,0.f,0.f};
  float hr[4] = {0.f,0.f,0.f,0.f};
  #pragma unroll
  for (int tc=0; tc<8; tc++){
    int cbase = tc*16 + cq;
    int h = tc>>1;
    #pragma unroll
    for (int r=0;r<4;r++){
      hl[h] = fmaf(acc[tc][r], sal[cbase+r], hl[h]);
      hr[h] = fmaf(acc[tc][r], sar[cbase+r], hr[h]);
    }
  }
  #pragma unroll
  for (int h=0;h<4;h++){
    hl[h] += __shfl_xor(hl[h],16); hl[h] += __shfl_xor(hl[h],32);
    hr[h] += __shfl_xor(hr[h],16); hr[h] += __shfl_xor(hr[h],32);
  }
  if (lane < 16 && row < N){
    *(float4*)&el[(size_t)row*4] = make_float4(hl[0],hl[1],hl[2],hl[3]);
    *(float4*)&er[(size_t)row*4] = make_float4(hr[0],hr[1],hr[2],hr[3]);
  }
}

// ---------------- fused edge-softmax + aggregation (H=4,D=32) ----------------
__global__ __launch_bounds__(256) void k_agg128(const uint32* __restrict__ Fu, const float* __restrict__ el,
                         const float* __restrict__ er, const int* __restrict__ row_ptr,
                         const int* __restrict__ csr_src, ushort* __restrict__ out, int N){
  __shared__ float wlds[4][272];
  int t = threadIdx.x;
  int lane = t & 63;
  int wv = t >> 6;
  int node = (blockIdx.x*blockDim.x + t)>>6;
  if (__builtin_amdgcn_readfirstlane(node) >= N) return;
  int h = lane>>4;
  int i0 = lane & 15;
  float erv = er[(size_t)node*4+h];
  int beg = row_ptr[node], end = row_ptr[node+1];
  int ubeg = __builtin_amdgcn_readfirstlane(beg);
  int uend = __builtin_amdgcn_readfirstlane(end);
  int udeg = uend - ubeg;
  int sv = (lane < udeg) ? csr_src[ubeg+lane] : 0;
  int sn[4]; float evv[4];
  #pragma unroll
  for (int j=0;j<4;j++) sn[j] = __shfl(sv, i0 + 16*j);
  #pragma unroll
  for (int j=0;j<4;j++) evv[j] = el[(size_t)sn[j]*4+h];
  float w4[4];
  #pragma unroll
  for (int j=0;j<4;j++){
    float ev = evv[j] + erv;
    ev = ev>0.f ? ev : 0.2f*ev;
    w4[j] = (i0 + 16*j < udeg) ? __expf(ev) : 0.f;
  }
  float dsum = (w4[0]+w4[1]) + (w4[2]+w4[3]);
  dsum += __shfl_xor(dsum, 1);
  dsum += __shfl_xor(dsum, 2);
  dsum += __shfl_xor(dsum, 4);
  dsum += __shfl_xor(dsum, 8);
  int wb = h*68 + i0;
  wlds[wv][wb   ] = w4[0];
  wlds[wv][wb+16] = w4[1];
  wlds[wv][wb+32] = w4[2];
  wlds[wv][wb+48] = w4[3];
  const int* sp = csr_src + ubeg;
  const float* wp = &wlds[wv][h*68];
  float acc0=0.f, acc1=0.f;
  int nm = udeg > 64 ? 64 : udeg;
  uint32 vb[8];
  #pragma unroll
  for (int k=0;k<8;k++) vb[k] = (k<nm) ? Fu[(size_t)sp[k]*64 + lane] : 0u;
  int i=0;
  for (; i+16<=nm; i+=8){
    uint32 vn[8];
    #pragma unroll
    for (int k=0;k<8;k++) vn[k] = Fu[(size_t)sp[i+8+k]*64 + lane];
    #pragma unroll
    for (int k=0;k<8;k++){
      float wi = wp[i+k];
      acc0 = fmaf(wi, bf16lo(vb[k]), acc0);
      acc1 = fmaf(wi, bf16hi(vb[k]), acc1);
    }
    #pragma unroll
    for (int k=0;k<8;k++) vb[k]=vn[k];
  }
  {
    int lim = nm - i; if (lim > 8) lim = 8;
    #pragma unroll
    for (int k=0;k<8;k++) if (k<lim){
      float wi = wp[i+k];
      acc0 = fmaf(wi, bf16lo(vb[k]), acc0);
      acc1 = fmaf(wi, bf16hi(vb[k]), acc1);
    }
    for (int e=i+8; e<nm; e++){
      float wi = wp[e];
      uint32 v = Fu[(size_t)sp[e]*64 + lane];
      acc0 = fmaf(wi, bf16lo(v), acc0);
      acc1 = fmaf(wi, bf16hi(v), acc1);
    }
  }
  if (udeg > 64){
    for (int e=64; e<udeg; e++){
      int s = sp[e];
      float x = el[(size_t)s*4+h] + erv;
      x = x>0.f?x:0.2f*x; x=__expf(x);
      uint32 v = Fu[(size_t)s*64+lane];
      dsum += x;
      acc0 = fmaf(x, bf16lo(v), acc0);
      acc1 = fmaf(x, bf16hi(v), acc1);
    }
  }
  float inv = 1.0f/dsum;
  float o0 = acc0*inv, o1 = acc1*inv;
  o0 = o0>0.f ? o0 : expm1f(o0);
  o1 = o1>0.f ? o1 : expm1f(o1);
  uint32 uo = bf16rn(o0) | (bf16rn(o1)<<16);
  *(uint32*)(out + (size_t)node*128 + lane*2) = uo;
}

// ---------------- layer-2: tiled GEMM [N,128(bf16)]x[128,40+2] -> bf16 Fb40(stride 64), el2, er2 ----------------
__global__ __launch_bounds__(256) void k_gemm42(const ushort* __restrict__ A, const float* __restrict__ W,
                        const float* __restrict__ al, const float* __restrict__ ar,
                        ushort* __restrict__ Fb, float* __restrict__ el, float* __restrict__ er, int N){
  __shared__ float wfull[128*48];
  __shared__ float hs[32][132];
  int t = threadIdx.x;
  int rowBase = blockIdx.x*128;
  for (int i=t; i<1280; i+=256){
    float4 v = *(const float4*)&W[i*4];
    int g = i*4;
    *(float4*)&wfull[(g/40)*48 + (g%40)] = v;
  }
  {
    int k = t & 127;
    const float* wrow = W + k*40;
    const float* a = (t < 128) ? al : ar;
    float s = 0.f;
    #pragma unroll
    for (int c=0;c<40;c++) s += wrow[c]*a[c];
    if (t < 128){
      wfull[k*48+40] = s;
      wfull[k*48+42] = 0.f; wfull[k*48+43] = 0.f; wfull[k*48+44] = 0.f;
    } else {
      wfull[k*48+41] = s;
      wfull[k*48+45] = 0.f; wfull[k*48+46] = 0.f; wfull[k*48+47] = 0.f;
    }
  }
  int c0 = (t&7)*6;
  int r0 = (t>>3)*4;
  float acc[4][6] = {};
  for (int kc=0; kc<128; kc+=32){
    {
      int row = t>>1; int kk0 = (t&1)*16;
      int grow = rowBase + row;
      if (grow < N){
        uint4 u0 = *(const uint4*)&A[(size_t)grow*128 + kc + kk0];
        uint4 u1 = *(const uint4*)&A[(size_t)grow*128 + kc + kk0 + 8];
        hs[kk0+ 0][row]=bf16lo(u0.x); hs[kk0+ 1][row]=bf16hi(u0.x);
        hs[kk0+ 2][row]=bf16lo(u0.y); hs[kk0+ 3][row]=bf16hi(u0.y);
        hs[kk0+ 4][row]=bf16lo(u0.z); hs[kk0+ 5][row]=bf16hi(u0.z);
        hs[kk0+ 6][row]=bf16lo(u0.w); hs[kk0+ 7][row]=bf16hi(u0.w);
        hs[kk0+ 8][row]=bf16lo(u1.x); hs[kk0+ 9][row]=bf16hi(u1.x);
        hs[kk0+10][row]=bf16lo(u1.y); hs[kk0+11][row]=bf16hi(u1.y);
        hs[kk0+12][row]=bf16lo(u1.z); hs[kk0+13][row]=bf16hi(u1.z);
        hs[kk0+14][row]=bf16lo(u1.w); hs[kk0+15][row]=bf16hi(u1.w);
      } else {
        #pragma unroll
        for (int j=0;j<16;j++) hs[kk0+j][row]=0.f;
      }
    }
    __syncthreads();
    #pragma unroll
    for (int k=0;k<32;k++){
      float4 av = *(const float4*)&hs[k][r0];
      const float* wp = &wfull[(kc+k)*48 + c0];
      float2 b01 = *(const float2*)&wp[0];
      float2 b23 = *(const float2*)&wp[2];
      float2 b45 = *(const float2*)&wp[4];
      float a4[4] = {av.x,av.y,av.z,av.w};
      float b6[6] = {b01.x,b01.y,b23.x,b23.y,b45.x,b45.y};
      #pragma unroll
      for (int r=0;r<4;r++)
        #pragma unroll
        for (int c=0;c<6;c++)
          acc[r][c] = fmaf(a4[r], b6[c], acc[r][c]);
    }
    __syncthreads();
  }
  #pragma unroll
  for (int r=0;r<4;r++){
    int row = rowBase + r0 + r;
    if (row >= N) break;
    if (c0 < 40){
      #pragma unroll
      for (int j=0;j<6;j+=2){
        int col = c0 + j;
        if (col < 40){
          uint32 u = bf16rn(acc[r][j]) | (bf16rn(acc[r][j+1])<<16);
          *(uint32*)(Fb + (size_t)row*FB40S + col) = u;
        }
      }
      if (c0 == 36){ el[row] = acc[r][4]; er[row] = acc[r][5]; }
    }
  }
}

// ---------------- final aggregation (H=1,D=40) + log_softmax ----------------
__global__ __launch_bounds__(256) void k_agg40(const ushort* __restrict__ Fb, const float* __restrict__ el,
                       const float* __restrict__ er, const int* __restrict__ row_ptr,
                       const int* __restrict__ csr_src, float* __restrict__ out, int N){
  __shared__ float wlds[4][64];
  int t = threadIdx.x;
  int lane = t & 63;
  int wv = t >> 6;
  int node = (blockIdx.x*blockDim.x + t)>>6;
  if (__builtin_amdgcn_readfirstlane(node) >= N) return;
  bool act = lane<40;
  int l40 = act ? lane : 0;
  float erv = er[node];
  int beg = row_ptr[node], end = row_ptr[node+1];
  int ubeg = __builtin_amdgcn_readfirstlane(beg);
  int uend = __builtin_amdgcn_readfirstlane(end);
  int udeg = uend - ubeg;
  int sv = (lane < udeg) ? csr_src[ubeg+lane] : 0;
  float w = 0.f;
  if (lane < udeg){
    float ev = el[sv] + erv;
    ev = ev>0.f ? ev : 0.2f*ev;
    w = __expf(ev);
  }
  float dsum = w;
  dsum += __shfl_xor(dsum, 1);
  dsum += __shfl_xor(dsum, 2);
  dsum += __shfl_xor(dsum, 4);
  dsum += __shfl_xor(dsum, 8);
  dsum += __shfl_xor(dsum, 16);
  dsum += __shfl_xor(dsum, 32);
  wlds[wv][lane] = w;
  const int* sp = csr_src + ubeg;
  float acc=0.f;
  int nm = udeg > 64 ? 64 : udeg;
  ushort fb8[8];
  #pragma unroll
  for (int k=0;k<8;k++) fb8[k] = (k<nm) ? Fb[(size_t)sp[k]*FB40S + l40] : (ushort)0;
  int i=0;
  for (; i+16<=nm; i+=8){
    ushort fn[8];
    #pragma unroll
    for (int k=0;k<8;k++) fn[k] = Fb[(size_t)sp[i+8+k]*FB40S + l40];
    #pragma unroll
    for (int k=0;k<8;k++){
      float wi = wlds[wv][i+k];
      acc = fmaf(wi, __uint_as_float(((uint32)fb8[k])<<16), acc);
    }
    #pragma unroll
    for (int k=0;k<8;k++) fb8[k]=fn[k];
  }
  {
    int lim = nm - i; if (lim > 8) lim = 8;
    #pragma unroll
    for (int k=0;k<8;k++) if (k<lim){
      float wi = wlds[wv][i+k];
      acc = fmaf(wi, __uint_as_float(((uint32)fb8[k])<<16), acc);
    }
    for (int e=i+8; e<nm; e++){
      float wi = wlds[wv][e];
      ushort f = Fb[(size_t)sp[e]*FB40S + l40];
      acc = fmaf(wi, __uint_as_float(((uint32)f)<<16), acc);
    }
  }
  if (udeg > 64){
    for (int e=64; e<udeg; e++){
      int s = sp[e];
      float x = el[s] + erv;
      x = x>0.f?x:0.2f*x; x=__expf(x);
      ushort f = Fb[(size_t)s*FB40S + l40];
      dsum += x;
      acc = fmaf(x, __uint_as_float(((uint32)f)<<16), acc);
    }
  }
  float logit = acc/dsum;
  float m = act ? logit : -INFINITY;
  for (int off=32; off; off>>=1) m = fmaxf(m, __shfl_xor(m, off));
  float ex = act ? expf(logit - m) : 0.f;
  float ssum = ex;
  for (int off=32; off; off>>=1) ssum += __shfl_xor(ssum, off);
  if (act) out[(size_t)node*40 + lane] = logit - m - logf(ssum);
}

extern "C" void kernel_launch(void* const* d_in, const int* in_sizes, int n_in,
                              void* d_out, int out_size, void* d_ws, size_t ws_size,
                              hipStream_t stream){
  const float* inputs = (const float*)d_in[0];
  const float* W0  = (const float*)d_in[1];
  const float* al0 = (const float*)d_in[2];
  const float* ar0 = (const float*)d_in[3];
  const float* W1  = (const float*)d_in[4];
  const float* al1 = (const float*)d_in[5];
  const float* ar1 = (const float*)d_in[6];
  const float* W2  = (const float*)d_in[7];
  const float* al2 = (const float*)d_in[8];
  const float* ar2 = (const float*)d_in[9];
  const int* src = (const int*)d_in[10];
  const int* dst = (const int*)d_in[11];
  int N = in_sizes[0]/128;
  int E = in_sizes[10];
  int NB = (N + (1<<BKT_SHIFT) - 1) >> BKT_SHIFT;

  char* p = (char*)d_ws;
  auto carve = [&](size_t bytes)->char*{ char* q=p; p += ((bytes+255)/256)*256; return q; };
  ushort* Fb   = (ushort*)carve((size_t)N*128*2);     // bf16 feat
  ushort* Fb40 = (ushort*)carve((size_t)N*FB40S*2);   // bf16 layer-2 feat (padded stride)
  ushort* bufH = (ushort*)carve((size_t)N*128*2);     // bf16 hidden; pairs alias this during CSR build
  float* el  = (float*)carve((size_t)N*4*4);
  float* er  = (float*)carve((size_t)N*4*4);
  float* el2 = (float*)carve((size_t)N*4);
  float* er2 = (float*)carve((size_t)N*4);
  int* bkt_cursor  = (int*)carve((size_t)NB*4);       // zero-init
  int* row_ptr = (int*)carve((size_t)(N+1)*4);
  int* csr_src = (int*)carve((size_t)E*4);

  uint32* pairs = (uint32*)bufH;                      // NB*BKTCAP*4 = 9.6 MB < 25.6 MB

  hipMemsetAsync(bkt_cursor, 0, (size_t)NB*4, stream);
  int nPB = (E + PCHUNK - 1) / PCHUNK;
  k_partition<<<nPB, 256, 0, stream>>>(src, dst, bkt_cursor, pairs, E);
  k_build    <<<NB, 1024, 0, stream>>>(bkt_cursor, NB, pairs, row_ptr, csr_src, N);

  int gRows = (N+63)/64;
  int gWave = (N+3)/4;
  int gRows42 = (N+127)/128;
  // layer 0
  k_gemm128_mfma<false><<<gRows,256,0,stream>>>(inputs, W0, al0, ar0, Fb, el, er, N);
  k_agg128 <<<gWave,256,0,stream>>>((const uint32*)Fb, el, er, row_ptr, csr_src, bufH, N);
  // layer 1
  k_gemm128_mfma<true><<<gRows,256,0,stream>>>(bufH, W1, al1, ar1, Fb, el, er, N);
  k_agg128 <<<gWave,256,0,stream>>>((const uint32*)Fb, el, er, row_ptr, csr_src, bufH, N);
  // layer 2
  k_gemm42 <<<gRows42,256,0,stream>>>(bufH, W2, al2, ar2, Fb40, el2, er2, N);
  k_agg40  <<<gWave,256,0,stream>>>(Fb40, el2, er2, row_ptr, csr_src, (float*)d_out, N);
}

// Round 10
// 340.591 us; speedup vs baseline: 3.0918x; 1.0210x over previous
//
#include <hip/hip_runtime.h>
#include <math.h>

typedef unsigned int uint32;
typedef unsigned short ushort;
typedef __attribute__((ext_vector_type(8))) short short8;
typedef __attribute__((ext_vector_type(4))) float f32x4;

__device__ inline uint32 bf16rn(float x){
  uint32 b = __float_as_uint(x);
  return (b + 0x7fffu + ((b>>16)&1u)) >> 16;
}
__device__ inline float bf16lo(uint32 v){ return __uint_as_float(v<<16); }
__device__ inline float bf16hi(uint32 v){ return __uint_as_float(v & 0xffff0000u); }

#define BKT_SHIFT 9            // 512 nodes per bucket
#define BKTCAP 12288           // per-bucket record capacity
#define PCHUNK 4096            // edges per partition block
#define FB40S 64               // padded row stride for layer-2 feat

// ---------------- fused: edge partition (blocks 0..nPB-1) + layer-0 MFMA GEMM (rest) ----------------
__global__ __launch_bounds__(256) void k_part_gemm0(const int* __restrict__ src, const int* __restrict__ dst,
                        int* __restrict__ bkt_cursor, uint32* __restrict__ pairs, int E, int nPB,
                        const float* __restrict__ A, const float* __restrict__ W,
                        const float* __restrict__ al, const float* __restrict__ ar,
                        ushort* __restrict__ Fb, float* __restrict__ el, float* __restrict__ er, int N){
  __shared__ __align__(16) ushort Wlds[128*128];
  __shared__ __align__(16) ushort Alds[64*128];
  __shared__ float sal[128], sar[128];
  int t = threadIdx.x;
  if (blockIdx.x < nPB){
    // ================= partition body =================
    int* cnt  = (int*)Wlds;          // reuse LDS
    int* base = ((int*)Wlds) + 512;
    int blockBase = blockIdx.x * PCHUNK;
    for (int i=t; i<512; i+=256) cnt[i]=0;
    __syncthreads();
    #pragma unroll
    for (int i=0; i<PCHUNK/1024; i++){
      int e0 = blockBase + (i*256 + t)*4;
      if (e0+3 < E){
        int4 d4 = *(const int4*)&dst[e0];
        atomicAdd(&cnt[d4.x>>BKT_SHIFT],1);
        atomicAdd(&cnt[d4.y>>BKT_SHIFT],1);
        atomicAdd(&cnt[d4.z>>BKT_SHIFT],1);
        atomicAdd(&cnt[d4.w>>BKT_SHIFT],1);
      } else {
        for (int e=e0; e<E && e<e0+4; e++) atomicAdd(&cnt[dst[e]>>BKT_SHIFT],1);
      }
    }
    __syncthreads();
    for (int i=t; i<512; i+=256){
      int c = cnt[i];
      base[i] = c ? atomicAdd(&bkt_cursor[i], c) : 0;
      cnt[i] = 0;
    }
    __syncthreads();
    #pragma unroll
    for (int i=0; i<PCHUNK/1024; i++){
      int e0 = blockBase + (i*256 + t)*4;
      if (e0+3 < E){
        int4 s4 = *(const int4*)&src[e0];
        int4 d4 = *(const int4*)&dst[e0];
        int bx, pos;
        bx=d4.x>>BKT_SHIFT; pos=base[bx]+atomicAdd(&cnt[bx],1); if(pos<BKTCAP) pairs[(size_t)bx*BKTCAP+pos]=(uint32)s4.x|((uint32)(d4.x&511)<<22);
        bx=d4.y>>BKT_SHIFT; pos=base[bx]+atomicAdd(&cnt[bx],1); if(pos<BKTCAP) pairs[(size_t)bx*BKTCAP+pos]=(uint32)s4.y|((uint32)(d4.y&511)<<22);
        bx=d4.z>>BKT_SHIFT; pos=base[bx]+atomicAdd(&cnt[bx],1); if(pos<BKTCAP) pairs[(size_t)bx*BKTCAP+pos]=(uint32)s4.z|((uint32)(d4.z&511)<<22);
        bx=d4.w>>BKT_SHIFT; pos=base[bx]+atomicAdd(&cnt[bx],1); if(pos<BKTCAP) pairs[(size_t)bx*BKTCAP+pos]=(uint32)s4.w|((uint32)(d4.w&511)<<22);
      } else {
        for (int e=e0; e<E && e<e0+4; e++){
          int s=src[e], d=dst[e];
          int bx=d>>BKT_SHIFT; int pos=base[bx]+atomicAdd(&cnt[bx],1);
          if(pos<BKTCAP) pairs[(size_t)bx*BKTCAP+pos]=(uint32)s|((uint32)(d&511)<<22);
        }
      }
    }
    return;
  }
  // ================= gemm0 body (A fp32) =================
  int rowBase = (blockIdx.x - nPB)*64;
  for (int i=t; i<8192; i+=256){
    int col = i & 127;
    int k2  = (i >> 7) * 2;
    float w0 = W[(size_t)k2*128 + col];
    float w1 = W[(size_t)(k2+1)*128 + col];
    uint32 pk = bf16rn(w0) | (bf16rn(w1)<<16);
    int byte = col*256 + k2*2;
    byte ^= (col&7)<<4;
    *(uint32*)((char*)Wlds + byte) = pk;
  }
  if (t < 128){ sal[t] = al[t]; sar[t] = ar[t]; }
  {
    int row = t>>2, k0 = (t&3)*32;
    int grow = rowBase + row;
    uint32 pk[16];
    if (grow < N){
      #pragma unroll
      for (int j=0;j<16;j++){
        float2 v = *(const float2*)(A + (size_t)grow*128 + k0 + j*2);
        pk[j] = bf16rn(v.x) | (bf16rn(v.y)<<16);
      }
    } else {
      #pragma unroll
      for (int j=0;j<16;j++) pk[j]=0u;
    }
    #pragma unroll
    for (int q=0;q<4;q++){
      int byte = row*256 + (k0 + q*8)*2;
      byte ^= (row&7)<<4;
      *(uint4*)((char*)Alds + byte) = make_uint4(pk[q*4],pk[q*4+1],pk[q*4+2],pk[q*4+3]);
    }
  }
  __syncthreads();
  int wid = t>>6, lane = t&63;
  int strip = wid*16;
  int lrow = lane & 15;
  int lk   = (lane>>4)*8;
  int swz  = (lrow&7)<<4;
  f32x4 acc[8];
  #pragma unroll
  for (int tc=0; tc<8; tc++) acc[tc] = (f32x4){0.f,0.f,0.f,0.f};
  #pragma unroll
  for (int kstep=0; kstep<4; kstep++){
    int kb = (kstep*32 + lk)*2;
    short8 bfrag = *(const short8*)((const char*)Alds + (((strip+lrow)*256 + kb) ^ swz));
    #pragma unroll
    for (int tc=0; tc<8; tc++){
      short8 afrag = *(const short8*)((const char*)Wlds + (((tc*16+lrow)*256 + kb) ^ swz));
      acc[tc] = __builtin_amdgcn_mfma_f32_16x16x32_bf16(afrag, bfrag, acc[tc], 0, 0, 0);
    }
  }
  int row = rowBase + strip + lrow;
  int cq = (lane>>4)*4;
  #pragma unroll
  for (int tc=0; tc<8; tc++){
    if (row < N){
      uint32 u0 = bf16rn(acc[tc][0]) | (bf16rn(acc[tc][1])<<16);
      uint32 u1 = bf16rn(acc[tc][2]) | (bf16rn(acc[tc][3])<<16);
      *(uint2*)(Fb + (size_t)row*128 + tc*16 + cq) = make_uint2(u0,u1);
    }
  }
  float hl[4] = {0.f,0.f,0.f,0.f};
  float hr[4] = {0.f,0.f,0.f,0.f};
  #pragma unroll
  for (int tc=0; tc<8; tc++){
    int cbase = tc*16 + cq;
    int h = tc>>1;
    #pragma unroll
    for (int r=0;r<4;r++){
      hl[h] = fmaf(acc[tc][r], sal[cbase+r], hl[h]);
      hr[h] = fmaf(acc[tc][r], sar[cbase+r], hr[h]);
    }
  }
  #pragma unroll
  for (int h=0;h<4;h++){
    hl[h] += __shfl_xor(hl[h],16); hl[h] += __shfl_xor(hl[h],32);
    hr[h] += __shfl_xor(hr[h],16); hr[h] += __shfl_xor(hr[h],32);
  }
  if (lane < 16 && row < N){
    *(float4*)&el[(size_t)row*4] = make_float4(hl[0],hl[1],hl[2],hl[3]);
    *(float4*)&er[(size_t)row*4] = make_float4(hr[0],hr[1],hr[2],hr[3]);
  }
}

// ---------------- per-bucket CSR build (scan of bucket totals folded in) ----------------
__global__ __launch_bounds__(1024) void k_build(const int* __restrict__ bkt_cursor, int nb,
                        const uint32* __restrict__ pairs,
                        int* __restrict__ row_ptr, int* __restrict__ csr_src, int N){
  __shared__ int bscan[256];
  __shared__ int hist[512];
  __shared__ int sc[512];
  __shared__ int cur[512];
  int b = blockIdx.x;
  int t = threadIdx.x;
  int v0 = (t<256 && t<nb) ? min(bkt_cursor[t], BKTCAP) : 0;
  if (t<256) bscan[t] = v0;
  __syncthreads();
  int x0 = v0;
  for (int off=1; off<256; off<<=1){
    int y = (t<256 && t>=off) ? bscan[t-off] : 0;
    __syncthreads();
    if (t<256){ x0 += y; bscan[t] = x0; }
    __syncthreads();
  }
  int base = (b==0) ? 0 : bscan[b-1];
  if (b==0 && t==0) row_ptr[N] = bscan[nb-1];
  int cnt = bkt_cursor[b]; if (cnt > BKTCAP) cnt = BKTCAP;
  const uint32* p = pairs + (size_t)b*BKTCAP;
  if (t<512) hist[t]=0;
  __syncthreads();
  for (int i=t; i<cnt; i+=1024) atomicAdd(&hist[p[i]>>22], 1);
  __syncthreads();
  int v = (t<512)? hist[t] : 0;
  if (t<512) sc[t]=v;
  __syncthreads();
  int x=v;
  for (int off=1; off<512; off<<=1){
    int y = (t<512 && t>=off)? sc[t-off] : 0;
    __syncthreads();
    if (t<512){ x+=y; sc[t]=x; }
    __syncthreads();
  }
  if (t<512){
    int excl = x - v;
    int gnode = (b<<BKT_SHIFT) + t;
    if (gnode < N) row_ptr[gnode] = base + excl;
    cur[t] = excl;
  }
  __syncthreads();
  for (int i=t; i<cnt; i+=1024){
    uint32 e = p[i];
    int pos = atomicAdd(&cur[e>>22], 1);
    csr_src[base + pos] = (int)(e & 0x3FFFFFu);
  }
}

// ---------------- MFMA GEMM [N,128(bf16)]x[128,128] -> bf16 F + fused el/er (layer 1) ----------------
__global__ __launch_bounds__(256) void k_gemm128_mfma(const ushort* __restrict__ Ab, const float* __restrict__ W,
                        const float* __restrict__ al, const float* __restrict__ ar,
                        ushort* __restrict__ Fb, float* __restrict__ el, float* __restrict__ er, int N){
  __shared__ __align__(16) ushort Wlds[128*128];
  __shared__ __align__(16) ushort Alds[64*128];
  __shared__ float sal[128], sar[128];
  int t = threadIdx.x;
  int rowBase = blockIdx.x*64;
  for (int i=t; i<8192; i+=256){
    int col = i & 127;
    int k2  = (i >> 7) * 2;
    float w0 = W[(size_t)k2*128 + col];
    float w1 = W[(size_t)(k2+1)*128 + col];
    uint32 pk = bf16rn(w0) | (bf16rn(w1)<<16);
    int byte = col*256 + k2*2;
    byte ^= (col&7)<<4;
    *(uint32*)((char*)Wlds + byte) = pk;
  }
  if (t < 128){ sal[t] = al[t]; sar[t] = ar[t]; }
  {
    int row = t>>2, k0 = (t&3)*32;
    int grow = rowBase + row;
    uint32 pk[16];
    if (grow < N){
      const uint4* ap = (const uint4*)(Ab + (size_t)grow*128 + k0);
      #pragma unroll
      for (int q=0;q<4;q++){ uint4 u = ap[q]; pk[q*4]=u.x; pk[q*4+1]=u.y; pk[q*4+2]=u.z; pk[q*4+3]=u.w; }
    } else {
      #pragma unroll
      for (int j=0;j<16;j++) pk[j]=0u;
    }
    #pragma unroll
    for (int q=0;q<4;q++){
      int byte = row*256 + (k0 + q*8)*2;
      byte ^= (row&7)<<4;
      *(uint4*)((char*)Alds + byte) = make_uint4(pk[q*4],pk[q*4+1],pk[q*4+2],pk[q*4+3]);
    }
  }
  __syncthreads();
  int wid = t>>6, lane = t&63;
  int strip = wid*16;
  int lrow = lane & 15;
  int lk   = (lane>>4)*8;
  int swz  = (lrow&7)<<4;
  f32x4 acc[8];
  #pragma unroll
  for (int tc=0; tc<8; tc++) acc[tc] = (f32x4){0.f,0.f,0.f,0.f};
  #pragma unroll
  for (int kstep=0; kstep<4; kstep++){
    int kb = (kstep*32 + lk)*2;
    short8 bfrag = *(const short8*)((const char*)Alds + (((strip+lrow)*256 + kb) ^ swz));
    #pragma unroll
    for (int tc=0; tc<8; tc++){
      short8 afrag = *(const short8*)((const char*)Wlds + (((tc*16+lrow)*256 + kb) ^ swz));
      acc[tc] = __builtin_amdgcn_mfma_f32_16x16x32_bf16(afrag, bfrag, acc[tc], 0, 0, 0);
    }
  }
  int row = rowBase + strip + lrow;
  int cq = (lane>>4)*4;
  #pragma unroll
  for (int tc=0; tc<8; tc++){
    if (row < N){
      uint32 u0 = bf16rn(acc[tc][0]) | (bf16rn(acc[tc][1])<<16);
      uint32 u1 = bf16rn(acc[tc][2]) | (bf16rn(acc[tc][3])<<16);
      *(uint2*)(Fb + (size_t)row*128 + tc*16 + cq) = make_uint2(u0,u1);
    }
  }
  float hl[4] = {0.f,0.f,0.f,0.f};
  float hr[4] = {0.f,0.f,0.f,0.f};
  #pragma unroll
  for (int tc=0; tc<8; tc++){
    int cbase = tc*16 + cq;
    int h = tc>>1;
    #pragma unroll
    for (int r=0;r<4;r++){
      hl[h] = fmaf(acc[tc][r], sal[cbase+r], hl[h]);
      hr[h] = fmaf(acc[tc][r], sar[cbase+r], hr[h]);
    }
  }
  #pragma unroll
  for (int h=0;h<4;h++){
    hl[h] += __shfl_xor(hl[h],16); hl[h] += __shfl_xor(hl[h],32);
    hr[h] += __shfl_xor(hr[h],16); hr[h] += __shfl_xor(hr[h],32);
  }
  if (lane < 16 && row < N){
    *(float4*)&el[(size_t)row*4] = make_float4(hl[0],hl[1],hl[2],hl[3]);
    *(float4*)&er[(size_t)row*4] = make_float4(hr[0],hr[1],hr[2],hr[3]);
  }
}

// ---------------- fused edge-softmax + aggregation (H=4,D=32) ----------------
__global__ __launch_bounds__(256) void k_agg128(const uint32* __restrict__ Fu, const float* __restrict__ el,
                         const float* __restrict__ er, const int* __restrict__ row_ptr,
                         const int* __restrict__ csr_src, ushort* __restrict__ out, int N){
  __shared__ float wlds[4][272];
  int t = threadIdx.x;
  int lane = t & 63;
  int wv = t >> 6;
  int node = (blockIdx.x*blockDim.x + t)>>6;
  if (__builtin_amdgcn_readfirstlane(node) >= N) return;
  int h = lane>>4;
  int i0 = lane & 15;
  float erv = er[(size_t)node*4+h];
  int beg = row_ptr[node], end = row_ptr[node+1];
  int ubeg = __builtin_amdgcn_readfirstlane(beg);
  int uend = __builtin_amdgcn_readfirstlane(end);
  int udeg = uend - ubeg;
  int sv = (lane < udeg) ? csr_src[ubeg+lane] : 0;
  int sn[4]; float evv[4];
  #pragma unroll
  for (int j=0;j<4;j++) sn[j] = __shfl(sv, i0 + 16*j);
  #pragma unroll
  for (int j=0;j<4;j++) evv[j] = el[(size_t)sn[j]*4+h];
  float w4[4];
  #pragma unroll
  for (int j=0;j<4;j++){
    float ev = evv[j] + erv;
    ev = ev>0.f ? ev : 0.2f*ev;
    w4[j] = (i0 + 16*j < udeg) ? __expf(ev) : 0.f;
  }
  float dsum = (w4[0]+w4[1]) + (w4[2]+w4[3]);
  dsum += __shfl_xor(dsum, 1);
  dsum += __shfl_xor(dsum, 2);
  dsum += __shfl_xor(dsum, 4);
  dsum += __shfl_xor(dsum, 8);
  int wb = h*68 + i0;
  wlds[wv][wb   ] = w4[0];
  wlds[wv][wb+16] = w4[1];
  wlds[wv][wb+32] = w4[2];
  wlds[wv][wb+48] = w4[3];
  const int* sp = csr_src + ubeg;
  const float* wp = &wlds[wv][h*68];
  float acc0=0.f, acc1=0.f;
  int nm = udeg > 64 ? 64 : udeg;
  uint32 vb[8];
  #pragma unroll
  for (int k=0;k<8;k++) vb[k] = (k<nm) ? Fu[(size_t)sp[k]*64 + lane] : 0u;
  int i=0;
  for (; i+16<=nm; i+=8){
    uint32 vn[8];
    #pragma unroll
    for (int k=0;k<8;k++) vn[k] = Fu[(size_t)sp[i+8+k]*64 + lane];
    #pragma unroll
    for (int k=0;k<8;k++){
      float wi = wp[i+k];
      acc0 = fmaf(wi, bf16lo(vb[k]), acc0);
      acc1 = fmaf(wi, bf16hi(vb[k]), acc1);
    }
    #pragma unroll
    for (int k=0;k<8;k++) vb[k]=vn[k];
  }
  {
    int lim = nm - i; if (lim > 8) lim = 8;
    #pragma unroll
    for (int k=0;k<8;k++) if (k<lim){
      float wi = wp[i+k];
      acc0 = fmaf(wi, bf16lo(vb[k]), acc0);
      acc1 = fmaf(wi, bf16hi(vb[k]), acc1);
    }
    for (int e=i+8; e<nm; e++){
      float wi = wp[e];
      uint32 v = Fu[(size_t)sp[e]*64 + lane];
      acc0 = fmaf(wi, bf16lo(v), acc0);
      acc1 = fmaf(wi, bf16hi(v), acc1);
    }
  }
  if (udeg > 64){
    for (int e=64; e<udeg; e++){
      int s = sp[e];
      float x = el[(size_t)s*4+h] + erv;
      x = x>0.f?x:0.2f*x; x=__expf(x);
      uint32 v = Fu[(size_t)s*64+lane];
      dsum += x;
      acc0 = fmaf(x, bf16lo(v), acc0);
      acc1 = fmaf(x, bf16hi(v), acc1);
    }
  }
  float inv = 1.0f/dsum;
  float o0 = acc0*inv, o1 = acc1*inv;
  o0 = o0>0.f ? o0 : expm1f(o0);
  o1 = o1>0.f ? o1 : expm1f(o1);
  uint32 uo = bf16rn(o0) | (bf16rn(o1)<<16);
  *(uint32*)(out + (size_t)node*128 + lane*2) = uo;
}

// ---------------- layer-2: tiled GEMM [N,128(bf16)]x[128,40+2] -> bf16 Fb40(stride 64), el2, er2 ----------------
__global__ __launch_bounds__(256) void k_gemm42(const ushort* __restrict__ A, const float* __restrict__ W,
                        const float* __restrict__ al, const float* __restrict__ ar,
                        ushort* __restrict__ Fb, float* __restrict__ el, float* __restrict__ er, int N){
  __shared__ float wfull[128*48];
  __shared__ float hs[32][132];
  int t = threadIdx.x;
  int rowBase = blockIdx.x*128;
  for (int i=t; i<1280; i+=256){
    float4 v = *(const float4*)&W[i*4];
    int g = i*4;
    *(float4*)&wfull[(g/40)*48 + (g%40)] = v;
  }
  {
    int k = t & 127;
    const float* wrow = W + k*40;
    const float* a = (t < 128) ? al : ar;
    float s = 0.f;
    #pragma unroll
    for (int c=0;c<40;c++) s += wrow[c]*a[c];
    if (t < 128){
      wfull[k*48+40] = s;
      wfull[k*48+42] = 0.f; wfull[k*48+43] = 0.f; wfull[k*48+44] = 0.f;
    } else {
      wfull[k*48+41] = s;
      wfull[k*48+45] = 0.f; wfull[k*48+46] = 0.f; wfull[k*48+47] = 0.f;
    }
  }
  int c0 = (t&7)*6;
  int r0 = (t>>3)*4;
  float acc[4][6] = {};
  for (int kc=0; kc<128; kc+=32){
    {
      int row = t>>1; int kk0 = (t&1)*16;
      int grow = rowBase + row;
      if (grow < N){
        uint4 u0 = *(const uint4*)&A[(size_t)grow*128 + kc + kk0];
        uint4 u1 = *(const uint4*)&A[(size_t)grow*128 + kc + kk0 + 8];
        hs[kk0+ 0][row]=bf16lo(u0.x); hs[kk0+ 1][row]=bf16hi(u0.x);
        hs[kk0+ 2][row]=bf16lo(u0.y); hs[kk0+ 3][row]=bf16hi(u0.y);
        hs[kk0+ 4][row]=bf16lo(u0.z); hs[kk0+ 5][row]=bf16hi(u0.z);
        hs[kk0+ 6][row]=bf16lo(u0.w); hs[kk0+ 7][row]=bf16hi(u0.w);
        hs[kk0+ 8][row]=bf16lo(u1.x); hs[kk0+ 9][row]=bf16hi(u1.x);
        hs[kk0+10][row]=bf16lo(u1.y); hs[kk0+11][row]=bf16hi(u1.y);
        hs[kk0+12][row]=bf16lo(u1.z); hs[kk0+13][row]=bf16hi(u1.z);
        hs[kk0+14][row]=bf16lo(u1.w); hs[kk0+15][row]=bf16hi(u1.w);
      } else {
        #pragma unroll
        for (int j=0;j<16;j++) hs[kk0+j][row]=0.f;
      }
    }
    __syncthreads();
    #pragma unroll
    for (int k=0;k<32;k++){
      float4 av = *(const float4*)&hs[k][r0];
      const float* wp = &wfull[(kc+k)*48 + c0];
      float2 b01 = *(const float2*)&wp[0];
      float2 b23 = *(const float2*)&wp[2];
      float2 b45 = *(const float2*)&wp[4];
      float a4[4] = {av.x,av.y,av.z,av.w};
      float b6[6] = {b01.x,b01.y,b23.x,b23.y,b45.x,b45.y};
      #pragma unroll
      for (int r=0;r<4;r++)
        #pragma unroll
        for (int c=0;c<6;c++)
          acc[r][c] = fmaf(a4[r], b6[c], acc[r][c]);
    }
    __syncthreads();
  }
  #pragma unroll
  for (int r=0;r<4;r++){
    int row = rowBase + r0 + r;
    if (row >= N) break;
    if (c0 < 40){
      #pragma unroll
      for (int j=0;j<6;j+=2){
        int col = c0 + j;
        if (col < 40){
          uint32 u = bf16rn(acc[r][j]) | (bf16rn(acc[r][j+1])<<16);
          *(uint32*)(Fb + (size_t)row*FB40S + col) = u;
        }
      }
      if (c0 == 36){ el[row] = acc[r][4]; er[row] = acc[r][5]; }
    }
  }
}

// ---------------- final aggregation (H=1,D=40) + log_softmax ----------------
__global__ __launch_bounds__(256) void k_agg40(const ushort* __restrict__ Fb, const float* __restrict__ el,
                       const float* __restrict__ er, const int* __restrict__ row_ptr,
                       const int* __restrict__ csr_src, float* __restrict__ out, int N){
  __shared__ float wlds[4][64];
  int t = threadIdx.x;
  int lane = t & 63;
  int wv = t >> 6;
  int node = (blockIdx.x*blockDim.x + t)>>6;
  if (__builtin_amdgcn_readfirstlane(node) >= N) return;
  bool act = lane<40;
  int l40 = act ? lane : 0;
  float erv = er[node];
  int beg = row_ptr[node], end = row_ptr[node+1];
  int ubeg = __builtin_amdgcn_readfirstlane(beg);
  int uend = __builtin_amdgcn_readfirstlane(end);
  int udeg = uend - ubeg;
  int sv = (lane < udeg) ? csr_src[ubeg+lane] : 0;
  float w = 0.f;
  if (lane < udeg){
    float ev = el[sv] + erv;
    ev = ev>0.f ? ev : 0.2f*ev;
    w = __expf(ev);
  }
  float dsum = w;
  dsum += __shfl_xor(dsum, 1);
  dsum += __shfl_xor(dsum, 2);
  dsum += __shfl_xor(dsum, 4);
  dsum += __shfl_xor(dsum, 8);
  dsum += __shfl_xor(dsum, 16);
  dsum += __shfl_xor(dsum, 32);
  wlds[wv][lane] = w;
  const int* sp = csr_src + ubeg;
  float acc=0.f;
  int nm = udeg > 64 ? 64 : udeg;
  ushort fb8[8];
  #pragma unroll
  for (int k=0;k<8;k++) fb8[k] = (k<nm) ? Fb[(size_t)sp[k]*FB40S + l40] : (ushort)0;
  int i=0;
  for (; i+16<=nm; i+=8){
    ushort fn[8];
    #pragma unroll
    for (int k=0;k<8;k++) fn[k] = Fb[(size_t)sp[i+8+k]*FB40S + l40];
    #pragma unroll
    for (int k=0;k<8;k++){
      float wi = wlds[wv][i+k];
      acc = fmaf(wi, __uint_as_float(((uint32)fb8[k])<<16), acc);
    }
    #pragma unroll
    for (int k=0;k<8;k++) fb8[k]=fn[k];
  }
  {
    int lim = nm - i; if (lim > 8) lim = 8;
    #pragma unroll
    for (int k=0;k<8;k++) if (k<lim){
      float wi = wlds[wv][i+k];
      acc = fmaf(wi, __uint_as_float(((uint32)fb8[k])<<16), acc);
    }
    for (int e=i+8; e<nm; e++){
      float wi = wlds[wv][e];
      ushort f = Fb[(size_t)sp[e]*FB40S + l40];
      acc = fmaf(wi, __uint_as_float(((uint32)f)<<16), acc);
    }
  }
  if (udeg > 64){
    for (int e=64; e<udeg; e++){
      int s = sp[e];
      float x = el[s] + erv;
      x = x>0.f?x:0.2f*x; x=__expf(x);
      ushort f = Fb[(size_t)s*FB40S + l40];
      dsum += x;
      acc = fmaf(x, __uint_as_float(((uint32)f)<<16), acc);
    }
  }
  float logit = acc/dsum;
  float m = act ? logit : -INFINITY;
  for (int off=32; off; off>>=1) m = fmaxf(m, __shfl_xor(m, off));
  float ex = act ? expf(logit - m) : 0.f;
  float ssum = ex;
  for (int off=32; off; off>>=1) ssum += __shfl_xor(ssum, off);
  if (act) out[(size_t)node*40 + lane] = logit - m - logf(ssum);
}

extern "C" void kernel_launch(void* const* d_in, const int* in_sizes, int n_in,
                              void* d_out, int out_size, void* d_ws, size_t ws_size,
                              hipStream_t stream){
  const float* inputs = (const float*)d_in[0];
  const float* W0  = (const float*)d_in[1];
  const float* al0 = (const float*)d_in[2];
  const float* ar0 = (const float*)d_in[3];
  const float* W1  = (const float*)d_in[4];
  const float* al1 = (const float*)d_in[5];
  const float* ar1 = (const float*)d_in[6];
  const float* W2  = (const float*)d_in[7];
  const float* al2 = (const float*)d_in[8];
  const float* ar2 = (const float*)d_in[9];
  const int* src = (const int*)d_in[10];
  const int* dst = (const int*)d_in[11];
  int N = in_sizes[0]/128;
  int E = in_sizes[10];
  int NB = (N + (1<<BKT_SHIFT) - 1) >> BKT_SHIFT;

  char* p = (char*)d_ws;
  auto carve = [&](size_t bytes)->char*{ char* q=p; p += ((bytes+255)/256)*256; return q; };
  ushort* Fb   = (ushort*)carve((size_t)N*128*2);     // bf16 feat
  ushort* Fb40 = (ushort*)carve((size_t)N*FB40S*2);   // bf16 layer-2 feat (padded stride)
  ushort* bufH = (ushort*)carve((size_t)N*128*2);     // bf16 hidden; pairs alias this during CSR build
  float* el  = (float*)carve((size_t)N*4*4);
  float* er  = (float*)carve((size_t)N*4*4);
  float* el2 = (float*)carve((size_t)N*4);
  float* er2 = (float*)carve((size_t)N*4);
  int* bkt_cursor  = (int*)carve((size_t)NB*4);       // zero-init
  int* row_ptr = (int*)carve((size_t)(N+1)*4);
  int* csr_src = (int*)carve((size_t)E*4);

  uint32* pairs = (uint32*)bufH;                      // NB*BKTCAP*4 = 9.6 MB < 25.6 MB

  hipMemsetAsync(bkt_cursor, 0, (size_t)NB*4, stream);
  int nPB = (E + PCHUNK - 1) / PCHUNK;
  int gRows = (N+63)/64;
  int gWave = (N+3)/4;
  int gRows42 = (N+127)/128;

  // fused: partition (blocks 0..nPB-1) + layer-0 GEMM (blocks nPB..nPB+gRows-1)
  k_part_gemm0<<<nPB+gRows, 256, 0, stream>>>(src, dst, bkt_cursor, pairs, E, nPB,
                                              inputs, W0, al0, ar0, Fb, el, er, N);
  k_build <<<NB, 1024, 0, stream>>>(bkt_cursor, NB, pairs, row_ptr, csr_src, N);
  // layer 0 aggregation
  k_agg128 <<<gWave,256,0,stream>>>((const uint32*)Fb, el, er, row_ptr, csr_src, bufH, N);
  // layer 1
  k_gemm128_mfma<<<gRows,256,0,stream>>>(bufH, W1, al1, ar1, Fb, el, er, N);
  k_agg128 <<<gWave,256,0,stream>>>((const uint32*)Fb, el, er, row_ptr, csr_src, bufH, N);
  // layer 2
  k_gemm42 <<<gRows42,256,0,stream>>>(bufH, W2, al2, ar2, Fb40, el2, er2, N);
  k_agg40  <<<gWave,256,0,stream>>>(Fb40, el2, er2, row_ptr, csr_src, (float*)d_out, N);
}